// Round 4
// baseline (281.679 us; speedup 1.0000x reference)
//
#include <hip/hip_runtime.h>
#include <hip/hip_bf16.h>
#include <math.h>

#define BB    1024
#define FIN   128
#define NOUT  10000
#define NBLK  79          // 128-col strips (fallback path)
#define NCB   158         // 64-col regions (Wbf layout)
#define NK    16
#define NPART (NCB * 2)   // fallback-path partial stride = 316
#define NPARTM NCB        // main-path partial stride = 158 (post LDS-combine)
#define LDX   136         // LDS stride (shorts) for the X tile

typedef __attribute__((ext_vector_type(8))) short short8;
typedef __attribute__((ext_vector_type(4))) float floatx4;

__device__ __forceinline__ unsigned packbf(float a, float b) {
    __hip_bfloat162 h = __float22bfloat162_rn(make_float2(a, b));
    union { __hip_bfloat162 h2; unsigned u; } v;
    v.h2 = h;
    return v.u;
}

// unpack bf16 pair, scale, repack
__device__ __forceinline__ unsigned scale2(unsigned p, float wi) {
    float lo = __uint_as_float(p << 16) * wi;
    float hi = __uint_as_float(p & 0xffff0000u) * wi;
    return packbf(lo, hi);
}

// async global->LDS, 16B per lane; LDS dest = wave-uniform base + lane*16.
__device__ __forceinline__ void async16(const void* g, void* l) {
    __builtin_amdgcn_global_load_lds(
        (const __attribute__((address_space(1))) unsigned int*)g,
        (__attribute__((address_space(3))) unsigned int*)l, 16, 0, 0);
}

// ---------------------------------------------------------------------------
// Kernel A (fallback path only)
__global__ void rowprep(const float* __restrict__ X, const float* __restrict__ factor,
                        float* __restrict__ xinv, float* __restrict__ fa_out,
                        float* __restrict__ thr_out) {
    int b = blockIdx.x;
    int lane = threadIdx.x;
    float v0 = X[b * FIN + lane];
    float v1 = X[b * FIN + 64 + lane];
    float s = v0 * v0 + v1 * v1;
    #pragma unroll
    for (int off = 32; off > 0; off >>= 1) s += __shfl_down(s, off);
    if (lane == 0) {
        xinv[b] = 1.0f / fmaxf(sqrtf(s), 1e-12f);
        float fa = powf(1.5f, factor[b] * (1.0f / 12.0f)) * 0.5f;
        fa_out[b] = fa;
        thr_out[b] = (float)M_PI - fa;
    }
}

// ---------------------------------------------------------------------------
// Kernel W v3 (proven): f-half staging (16 KB) + deferred winv scale at
// copy-out. LDS ~33.5 KB -> 4 blocks/CU. Wbf layout: per (k, cb64) 16 KB
// region [wn2(2)][n2(2)][kk(4)][lane=q*16+l15][16B], holding bf16(W * winv),
// o = cb*64 + wn2*32 + n2*16 + l15, f=(kk*4+q)*8..+7.
__global__ __launch_bounds__(256) void wconv(
    const float* __restrict__ W, unsigned char* __restrict__ Wbf,
    const float* __restrict__ X, const float* __restrict__ factor,
    float* __restrict__ xinv, float* __restrict__ fa_out, float* __restrict__ thr_out) {

    __shared__ float s[64 * 64];    // 16 KB: one f-half, [f][c] fp32
    __shared__ uint4 wout[1024];    // 16 KB packed (unscaled bf16)
    __shared__ float sq2[256];
    __shared__ float wis[64];

    const int tid = threadIdx.x;

    // rowprep tail blocks
    if (blockIdx.x >= NK * NCB) {
        int rb = blockIdx.x - NK * NCB;   // 0..15
        int w4 = tid >> 6, lane = tid & 63;
        for (int i = w4; i < 64; i += 4) {
            int row = rb * 64 + i;
            float v0 = X[row * FIN + lane];
            float v1 = X[row * FIN + 64 + lane];
            float ss = v0 * v0 + v1 * v1;
            #pragma unroll
            for (int off = 32; off > 0; off >>= 1) ss += __shfl_down(ss, off);
            if (lane == 0) {
                xinv[row] = 1.0f / fmaxf(sqrtf(ss), 1e-12f);
                float fa = powf(1.5f, factor[row] * (1.0f / 12.0f)) * 0.5f;
                fa_out[row] = fa;
                thr_out[row] = (float)M_PI - fa;
            }
        }
        return;
    }

    const int k  = blockIdx.x / NCB;
    const int cb = blockIdx.x - k * NCB;
    const int o0 = cb * 64;
    const int col = tid & 63, seg = tid >> 6;
    const int c   = tid >> 2, sub = tid & 3;
    const int wn_ = c >> 5, n2_ = (c >> 4) & 1, l15_ = c & 15;

    float sqacc = 0.0f;
    #pragma unroll
    for (int h = 0; h < 2; h++) {
        // stage f-half h: 64 rows x 64 cols fp32, coalesced
        #pragma unroll
        for (int it = 0; it < 4; it++) {
            int idx = it * 256 + tid;      // float4 idx 0..1023
            int f = idx >> 4, c4 = idx & 15;
            int o = o0 + c4 * 4;
            float4 v = make_float4(0.f, 0.f, 0.f, 0.f);
            if (o < NOUT)
                v = *(const float4*)(W + (size_t)(k * FIN + h * 64 + f) * NOUT + o);
            *(float4*)(s + f * 64 + c4 * 4) = v;
        }
        __syncthreads();
        // partial sumsq (16 f per thread)
        float ss = 0.0f;
        #pragma unroll
        for (int f2 = 0; f2 < 16; f2++) {
            float x = s[(seg * 16 + f2) * 64 + col];
            ss = fmaf(x, x, ss);
        }
        sqacc += ss;
        // pack this half UNSCALED
        #pragma unroll
        for (int i = 0; i < 2; i++) {
            int tcl = sub * 2 + i;          // 0..7
            int tcg = h * 8 + tcl;          // 0..15
            int kk = tcg >> 2, qq = tcg & 3;
            int fb = tcl * 8;               // LDS f-row base
            uint4 u;
            u.x = packbf(s[(fb + 0) * 64 + c], s[(fb + 1) * 64 + c]);
            u.y = packbf(s[(fb + 2) * 64 + c], s[(fb + 3) * 64 + c]);
            u.z = packbf(s[(fb + 4) * 64 + c], s[(fb + 5) * 64 + c]);
            u.w = packbf(s[(fb + 6) * 64 + c], s[(fb + 7) * 64 + c]);
            wout[wn_ * 512 + n2_ * 256 + kk * 64 + qq * 16 + l15_] = u;
        }
        __syncthreads();   // pack reads done before restage / before copy-out
    }
    sq2[tid] = sqacc;
    __syncthreads();
    if (tid < 64)
        wis[tid] = 1.0f / fmaxf(sqrtf(sq2[tid] + sq2[tid + 64] + sq2[tid + 128] + sq2[tid + 192]), 1e-12f);
    __syncthreads();

    // scaled coalesced copy-out
    unsigned char* dst = Wbf + ((size_t)k * NCB + cb) * 16384;
    #pragma unroll
    for (int i = 0; i < 4; i++) {
        int idx = i * 256 + tid;
        int ccol = ((idx >> 9) << 5) + (((idx >> 8) & 1) << 4) + (idx & 15);
        float wi = wis[ccol];
        uint4 u = wout[idx];
        uint4 r;
        r.x = scale2(u.x, wi);
        r.y = scale2(u.y, wi);
        r.z = scale2(u.z, wi);
        r.w = scale2(u.w, wi);
        *(uint4*)(dst + (size_t)idx * 16) = r;
    }
}

// ---------------------------------------------------------------------------
// Kernel B v4: wave geometry 2m x 4n (wave tile 64 rows x 16 cols) to halve
// redundant B LDS reads (r2 PMC: LDS-pipe bound, MfmaUtil 31% == 320/1024
// LDS cyc). Per k-step per wave: 4 ds_read_b128 (was 8), 16 MFMA (unchanged),
// each B frag feeds 4 MFMAs (was 2). 3-buffer counted-vmcnt pipeline kept
// verbatim from r2 (proven: VGPR 48, no spills). Epilogue: 4 wn-slabs per
// row combined via 4 KB LDS (dead B-buffer space) -> partial stride 158.
__global__ __launch_bounds__(512, 2) void gemm_mx(
    const float* __restrict__ X, const unsigned char* __restrict__ Wbf,
    const int* __restrict__ label, const float* __restrict__ xinv,
    float2* __restrict__ partial, float* __restrict__ cosl) {

    __shared__ union {
        short xs[128 * LDX];     // 34816 B, X staging
        short bb[3][8192];       // 3 x 16 KB B buffers = 49152 B
        float2 ms[128][4];       // 4 KB slab-stats combine (after loop only)
    } u;

    const int tid  = threadIdx.x;
    const int lane = tid & 63;
    const int w    = tid >> 6;     // 0..7
    const int l15  = lane & 15;
    const int q    = lane >> 4;
    const int wm   = w & 1;        // 2 m-slots (64 rows each)
    const int wn   = w >> 1;       // 4 n-slots (16 cols each)

    // XCD-aware decode: ids {group*64 + y*8 + xcd} -> cb = group*8 + xcd
    const int id    = blockIdx.x;
    const int group = id >> 6;
    const int sub   = id & 63;
    const int cb    = group * 8 + (sub & 7);
    const int y     = sub >> 3;            // 0..7
    if (cb >= NCB) return;
    const int r0 = y * 128;
    const int o0 = cb * 64;

    // ---- stage X tile (128 rows) as bf16 with xinv folded ----
    #pragma unroll
    for (int it = 0; it < 8; it++) {
        int idx = it * 512 + tid;      // float4 index 0..4095
        int row = idx >> 5;
        int c4  = idx & 31;
        const float4 v = *(const float4*)(X + (size_t)(r0 + row) * FIN + c4 * 4);
        float xi = xinv[r0 + row];
        uint2 p;
        p.x = packbf(v.x * xi, v.y * xi);
        p.y = packbf(v.z * xi, v.w * xi);
        *(uint2*)(u.xs + row * LDX + c4 * 4) = p;
    }
    __syncthreads();

    // A fragments: 4 m-tiles (wm*64 .. +63) x 4 kk
    short8 af[4][4];
    #pragma unroll
    for (int mt = 0; mt < 4; mt++)
        #pragma unroll
        for (int kk = 0; kk < 4; kk++)
            af[mt][kk] = *(const short8*)(u.xs + (wm * 64 + mt * 16 + l15) * LDX + kk * 32 + q * 8);
    __syncthreads();   // X area now reusable as B buffers

    // per-step B staging: 16 KB; wave w loads 2 KB (2 async16 calls)
    auto issue = [&](int k, short* d) {
        const unsigned char* g = Wbf + ((size_t)k * NCB + cb) * 16384
                                 + (size_t)w * 2048 + (size_t)lane * 16;
        short* dw = d + w * 1024;
        async16(g, dw);
        async16(g + 1024, dw + 512);
    };

    short* rd = u.bb[0];   // holds loads(k)
    short* nx = u.bb[1];   // holds loads(k+1), in flight
    short* wr = u.bb[2];   // free; receives loads(k+2)

    issue(0, rd);
    issue(1, nx);

    floatx4 maxv[4];
    #pragma unroll
    for (int mt = 0; mt < 4; mt++)
        #pragma unroll
        for (int r = 0; r < 4; r++)
            maxv[mt][r] = -INFINITY;

    const int wboff = wn * 2048 + lane * 8;   // (wn2*4096 + n2*2048) folded

    for (int k = 0; k < NK; k++) {
        // counted wait: my loads(k) done; loads(k+1) stay in flight
        if (k == NK - 1) {
            asm volatile("s_waitcnt vmcnt(0)" ::: "memory");
        } else {
            asm volatile("s_waitcnt vmcnt(2)" ::: "memory");
        }
        __builtin_amdgcn_s_barrier();
        if (k < NK - 2) issue(k + 2, wr);

        const short* wt = rd + wboff;

        floatx4 acc[4];
        #pragma unroll
        for (int mt = 0; mt < 4; mt++)
            acc[mt] = (floatx4){0.f, 0.f, 0.f, 0.f};
        #pragma unroll
        for (int kk = 0; kk < 4; kk++) {
            short8 bf = *(const short8*)(wt + kk * 512);
            #pragma unroll
            for (int mt = 0; mt < 4; mt++)
                acc[mt] = __builtin_amdgcn_mfma_f32_16x16x32_bf16(
                    af[mt][kk], bf, acc[mt], 0, 0, 0);
        }
        #pragma unroll
        for (int mt = 0; mt < 4; mt++)
            #pragma unroll
            for (int r = 0; r < 4; r++)
                maxv[mt][r] = fmaxf(maxv[mt][r], acc[mt][r]);

        // rotate buffers: rd <- nx <- wr <- old rd
        short* t = rd; rd = nx; nx = wr; wr = t;
    }

    // ---- epilogue: per-slab stats (16 cols), then LDS combine of 4 slabs ----
    __syncthreads();   // all B-buffer ds_reads done; LDS reusable as ms[][]

    #pragma unroll
    for (int mt = 0; mt < 4; mt++) {
        #pragma unroll
        for (int rr = 0; rr < 4; rr++) {
            int rloc = wm * 64 + mt * 16 + q * 4 + rr;
            int row = r0 + rloc;
            int lb = label[row];
            float m = -1e30f, sum = 0.f;
            int o = o0 + wn * 16 + l15;
            if (o < NOUT) {
                float cc = maxv[mt][rr];
                if (o == lb) {
                    cosl[row] = cc;   // unique writer grid-wide
                } else {
                    float l = 64.0f * fminf(fmaxf(cc, -1.0f + 1e-6f), 1.0f - 1e-6f);
                    sum = __expf(l - 64.0f);
                    m = l;
                }
            }
            #pragma unroll
            for (int off = 1; off <= 8; off <<= 1) {
                sum += __shfl_xor(sum, off);
                m = fmaxf(m, __shfl_xor(m, off));
            }
            if (l15 == 0)
                u.ms[rloc][wn] = make_float2(m, sum);
        }
    }
    __syncthreads();

    if (tid < 128) {
        float2 a = u.ms[tid][0], b = u.ms[tid][1];
        float2 c2 = u.ms[tid][2], d = u.ms[tid][3];
        float m = fmaxf(fmaxf(a.x, b.x), fmaxf(c2.x, d.x));
        float s = (a.y + b.y) + (c2.y + d.y);
        partial[(size_t)(r0 + tid) * NPARTM + cb] = make_float2(m, s);
    }
}

// ---------------------------------------------------------------------------
// Fallback GEMM (used when ws_size can't hold Wbf). Stride NPART partials.
__global__ __launch_bounds__(256, 2) void gemm_stats(
    const float* __restrict__ X, const float* __restrict__ W,
    const int* __restrict__ label, const float* __restrict__ xinv,
    float2* __restrict__ partial, float* __restrict__ cosl) {

    __shared__ short xs[128 * LDX];
    __shared__ short wt[128 * LDX];
    __shared__ float sqs[128][2];

    const int tid  = threadIdx.x;
    const int lane = tid & 63;
    const int w    = tid >> 6;
    const int l15  = lane & 15;
    const int q    = lane >> 4;
    const int wm   = w & 1;
    const int wn   = w >> 1;

    const int id    = blockIdx.x;
    const int group = id >> 6;
    const int sub   = id & 63;
    const int jb    = group * 8 + (sub & 7);
    const int y     = sub >> 3;
    if (jb >= NBLK) return;
    const int r0 = y * 128;
    const int o0 = jb * 128;

    #pragma unroll
    for (int it = 0; it < 16; it++) {
        int idx = it * 256 + tid;
        int row = idx >> 5;
        int c4  = idx & 31;
        const float4 v = *(const float4*)(X + (size_t)(r0 + row) * FIN + c4 * 4);
        uint2 p;
        p.x = packbf(v.x, v.y);
        p.y = packbf(v.z, v.w);
        *(uint2*)(xs + row * LDX + c4 * 4) = p;
    }

    const int st_o = (w & 1) * 64 + lane;
    const int st_f = (w >> 1) * 64;
    const int st_h = w >> 1;
    const int go   = o0 + st_o;
    const bool ov  = go < NOUT;

    float rw[64];
    {
        const float* Wp = W + (size_t)st_f * NOUT + go;
        #pragma unroll
        for (int g = 0; g < 16; g++)
            #pragma unroll
            for (int cc = 0; cc < 4; cc++)
                rw[g * 4 + cc] = ov ? Wp[(size_t)(g * 4 + cc) * NOUT] : 0.0f;
    }
    __syncthreads();

    short8 af[4][4];
    #pragma unroll
    for (int mt = 0; mt < 4; mt++)
        #pragma unroll
        for (int kk = 0; kk < 4; kk++)
            af[mt][kk] = *(const short8*)(xs + (wm * 64 + mt * 16 + l15) * LDX + kk * 32 + q * 8);

    floatx4 maxv[4][4];
    #pragma unroll
    for (int mt = 0; mt < 4; mt++)
        #pragma unroll
        for (int nt = 0; nt < 4; nt++)
            #pragma unroll
            for (int r = 0; r < 4; r++)
                maxv[mt][nt][r] = -INFINITY;

    for (int k = 0; k < NK; k++) {
        float sq = 0.0f;
        uint2 pk[16];
        #pragma unroll
        for (int g = 0; g < 16; g++) {
            float a0 = rw[g * 4 + 0], a1 = rw[g * 4 + 1];
            float a2 = rw[g * 4 + 2], a3 = rw[g * 4 + 3];
            sq = fmaf(a0, a0, sq); sq = fmaf(a1, a1, sq);
            sq = fmaf(a2, a2, sq); sq = fmaf(a3, a3, sq);
            pk[g].x = packbf(a0, a1);
            pk[g].y = packbf(a2, a3);
        }
        __syncthreads();
        #pragma unroll
        for (int g = 0; g < 16; g++)
            *(uint2*)(wt + st_o * LDX + st_f + g * 4) = pk[g];
        sqs[st_o][st_h] = sq;
        __syncthreads();

        if (k < NK - 1) {
            const float* Wn = W + ((size_t)(k + 1) * FIN + st_f) * NOUT + go;
            #pragma unroll
            for (int g = 0; g < 16; g++)
                #pragma unroll
                for (int cc = 0; cc < 4; cc++)
                    rw[g * 4 + cc] = ov ? Wn[(size_t)(g * 4 + cc) * NOUT] : 0.0f;
        }

        float wv[4];
        #pragma unroll
        for (int nt = 0; nt < 4; nt++) {
            int colx = wn * 64 + nt * 16 + l15;
            wv[nt] = 1.0f / fmaxf(sqrtf(sqs[colx][0] + sqs[colx][1]), 1e-12f);
        }

        #pragma unroll
        for (int h = 0; h < 2; h++) {
            floatx4 acc[4][2];
            #pragma unroll
            for (int mt = 0; mt < 4; mt++) {
                acc[mt][0] = (floatx4){0.f, 0.f, 0.f, 0.f};
                acc[mt][1] = (floatx4){0.f, 0.f, 0.f, 0.f};
            }
            #pragma unroll
            for (int kk = 0; kk < 4; kk++) {
                short8 bf0 = *(const short8*)(wt + (wn * 64 + (h * 2 + 0) * 16 + l15) * LDX + kk * 32 + q * 8);
                short8 bf1 = *(const short8*)(wt + (wn * 64 + (h * 2 + 1) * 16 + l15) * LDX + kk * 32 + q * 8);
                #pragma unroll
                for (int mt = 0; mt < 4; mt++) {
                    acc[mt][0] = __builtin_amdgcn_mfma_f32_16x16x32_bf16(af[mt][kk], bf0, acc[mt][0], 0, 0, 0);
                    acc[mt][1] = __builtin_amdgcn_mfma_f32_16x16x32_bf16(af[mt][kk], bf1, acc[mt][1], 0, 0, 0);
                }
            }
            #pragma unroll
            for (int mt = 0; mt < 4; mt++)
                #pragma unroll
                for (int n2 = 0; n2 < 2; n2++)
                    #pragma unroll
                    for (int r = 0; r < 4; r++)
                        maxv[mt][h * 2 + n2][r] =
                            fmaxf(maxv[mt][h * 2 + n2][r], acc[mt][n2][r] * wv[h * 2 + n2]);
        }
    }

    #pragma unroll
    for (int mt = 0; mt < 4; mt++) {
        #pragma unroll
        for (int rr = 0; rr < 4; rr++) {
            int row = r0 + wm * 64 + mt * 16 + q * 4 + rr;
            float xi = xinv[row];
            int lb = label[row];
            float m = -1e30f, sum = 0.f;
            #pragma unroll
            for (int nt = 0; nt < 4; nt++) {
                int o = o0 + wn * 64 + nt * 16 + l15;
                if (o < NOUT) {
                    float cc = maxv[mt][nt][rr] * xi;
                    if (o == lb) {
                        cosl[row] = cc;
                    } else {
                        float l = 64.0f * fminf(fmaxf(cc, -1.0f + 1e-6f), 1.0f - 1e-6f);
                        sum += __expf(l - 64.0f);
                        m = fmaxf(m, l);
                    }
                }
            }
            #pragma unroll
            for (int off = 1; off <= 8; off <<= 1) {
                sum += __shfl_xor(sum, off);
                m = fmaxf(m, __shfl_xor(m, off));
            }
            if (l15 == 0) {
                partial[(size_t)row * NPART + jb * 4 + wn * 2 + 0] = make_float2(m, sum);
                partial[(size_t)row * NPART + jb * 4 + wn * 2 + 1] = make_float2(-1e30f, 0.f);
            }
        }
    }
}

// ---------------------------------------------------------------------------
// Kernel C1: per-row combine (fixed-ref: plain sum+max) + margin. np = stride.
__global__ void finalize_rows(const float2* __restrict__ partial, const float* __restrict__ cosl,
                              const float* __restrict__ fa, const float* __restrict__ thr,
                              float2* __restrict__ rowres, int np) {
    int w = threadIdx.x >> 6;
    int lane = threadIdx.x & 63;
    int b = blockIdx.x * 4 + w;
    float m = -1e30f, s = 0.0f;
    for (int j = lane; j < np; j += 64) {
        float2 p = partial[(size_t)b * np + j];
        s += p.y;
        m = fmaxf(m, p.x);
    }
    #pragma unroll
    for (int off = 1; off < 64; off <<= 1) {
        s += __shfl_xor(s, off);
        m = fmaxf(m, __shfl_xor(m, off));
    }
    if (lane == 0) {
        float c = fminf(fmaxf(cosl[b], -1.0f + 1e-6f), 1.0f - 1e-6f);
        float theta = acosf(c);
        float ll = (theta > thr[b]) ? 64.0f * c : 64.0f * cosf(theta + fa[b]);
        float S = s + __expf(ll - 64.0f);
        float loss = 64.0f + logf(S) - ll;
        rowres[b] = make_float2(loss, (ll > m) ? 100.0f : 0.0f);
    }
}

// Kernel C2: deterministic tree reduce of 1024 rows -> 2 scalars.
__global__ void finalize_sum(const float2* __restrict__ rowres, float* __restrict__ out) {
    __shared__ float sl[1024];
    __shared__ float sc[1024];
    int b = threadIdx.x;
    float2 v = rowres[b];
    sl[b] = v.x;
    sc[b] = v.y;
    __syncthreads();
    for (int st = 512; st > 0; st >>= 1) {
        if (b < st) { sl[b] += sl[b + st]; sc[b] += sc[b + st]; }
        __syncthreads();
    }
    if (b == 0) {
        out[0] = sl[0] * (1.0f / 1024.0f);
        out[1] = sc[0] * (1.0f / 1024.0f);
    }
}

// ---------------------------------------------------------------------------
extern "C" void kernel_launch(void* const* d_in, const int* in_sizes, int n_in,
                              void* d_out, int out_size, void* d_ws, size_t ws_size,
                              hipStream_t stream) {
    const float* X      = (const float*)d_in[0];
    const float* factor = (const float*)d_in[1];
    const int*   label  = (const int*)d_in[2];
    const float* W      = (const float*)d_in[3];
    float* out = (float*)d_out;
    float* ws  = (float*)d_ws;

    float*  xinv = ws;                        // 1024
    float*  fa   = ws + 1024;                 // 1024
    float*  thr  = ws + 2048;                 // 1024
    float*  cosl = ws + 3072;                 // 1024
    float2* rowres = (float2*)(ws + 4096);    // 1024 float2
    float2* partial = (float2*)(ws + 6144);   // 1024 x 316 float2 max (~2.6 MB)
    unsigned char* Wbf = (unsigned char*)d_ws + 4 * 1024 * 1024;  // 41.4 MB

    const size_t wbf_bytes = (size_t)NK * NCB * 16384;
    const size_t need = 4ull * 1024 * 1024 + wbf_bytes;

    if (ws_size >= need) {
        wconv<<<NK * NCB + 16, 256, 0, stream>>>(W, Wbf, X, factor, xinv, fa, thr);
        gemm_mx<<<1280, 512, 0, stream>>>(X, Wbf, label, xinv, partial, cosl);
        finalize_rows<<<BB / 4, 256, 0, stream>>>(partial, cosl, fa, thr, rowres, NPARTM);
    } else {
        rowprep<<<BB, 64, 0, stream>>>(X, factor, xinv, fa, thr);
        gemm_stats<<<640, 256, 0, stream>>>(X, W, label, xinv, partial, cosl);
        finalize_rows<<<BB / 4, 256, 0, stream>>>(partial, cosl, fa, thr, rowres, NPART);
    }
    finalize_sum<<<1, BB, 0, stream>>>(rowres, out);
}

// Round 5
// 274.863 us; speedup vs baseline: 1.0248x; 1.0248x over previous
//
#include <hip/hip_runtime.h>
#include <hip/hip_bf16.h>
#include <math.h>

#define BB    1024
#define FIN   128
#define NOUT  10000
#define NBLK  79          // 128-col strips (fallback path)
#define NCB   158         // 64-col regions (Wbf layout)
#define NK    16
#define NPART (NCB * 2)   // fallback-path partial stride = 316
#define NPARTM NCB        // main-path partial stride = 158 (post LDS-combine)
#define LDX   136         // LDS stride (shorts) for the X tile

typedef __attribute__((ext_vector_type(8))) short short8;
typedef __attribute__((ext_vector_type(4))) float floatx4;

__device__ __forceinline__ unsigned packbf(float a, float b) {
    __hip_bfloat162 h = __float22bfloat162_rn(make_float2(a, b));
    union { __hip_bfloat162 h2; unsigned u; } v;
    v.h2 = h;
    return v.u;
}

// unpack bf16 pair, scale, repack
__device__ __forceinline__ unsigned scale2(unsigned p, float wi) {
    float lo = __uint_as_float(p << 16) * wi;
    float hi = __uint_as_float(p & 0xffff0000u) * wi;
    return packbf(lo, hi);
}

// async global->LDS, 16B per lane; LDS dest = wave-uniform base + lane*16.
__device__ __forceinline__ void async16(const void* g, void* l) {
    __builtin_amdgcn_global_load_lds(
        (const __attribute__((address_space(1))) unsigned int*)g,
        (__attribute__((address_space(3))) unsigned int*)l, 16, 0, 0);
}

// ---------------------------------------------------------------------------
// Kernel A (fallback path only)
__global__ void rowprep(const float* __restrict__ X, const float* __restrict__ factor,
                        float* __restrict__ xinv, float* __restrict__ fa_out,
                        float* __restrict__ thr_out) {
    int b = blockIdx.x;
    int lane = threadIdx.x;
    float v0 = X[b * FIN + lane];
    float v1 = X[b * FIN + 64 + lane];
    float s = v0 * v0 + v1 * v1;
    #pragma unroll
    for (int off = 32; off > 0; off >>= 1) s += __shfl_down(s, off);
    if (lane == 0) {
        xinv[b] = 1.0f / fmaxf(sqrtf(s), 1e-12f);
        float fa = powf(1.5f, factor[b] * (1.0f / 12.0f)) * 0.5f;
        fa_out[b] = fa;
        thr_out[b] = (float)M_PI - fa;
    }
}

// ---------------------------------------------------------------------------
// Kernel W v3 (proven): f-half staging (16 KB) + deferred winv scale at
// copy-out. LDS ~33.5 KB -> 4 blocks/CU. Wbf layout: per (k, cb64) 16 KB
// region [s(4 col-slabs of 16)][kk(4)][lane=q*16+l15][16B], holding
// bf16(W * winv), o = cb*64 + s*16 + l15, f=(kk*4+q)*8..+7.
__global__ __launch_bounds__(256) void wconv(
    const float* __restrict__ W, unsigned char* __restrict__ Wbf,
    const float* __restrict__ X, const float* __restrict__ factor,
    float* __restrict__ xinv, float* __restrict__ fa_out, float* __restrict__ thr_out) {

    __shared__ float s[64 * 64];    // 16 KB: one f-half, [f][c] fp32
    __shared__ uint4 wout[1024];    // 16 KB packed (unscaled bf16)
    __shared__ float sq2[256];
    __shared__ float wis[64];

    const int tid = threadIdx.x;

    // rowprep tail blocks
    if (blockIdx.x >= NK * NCB) {
        int rb = blockIdx.x - NK * NCB;   // 0..15
        int w4 = tid >> 6, lane = tid & 63;
        for (int i = w4; i < 64; i += 4) {
            int row = rb * 64 + i;
            float v0 = X[row * FIN + lane];
            float v1 = X[row * FIN + 64 + lane];
            float ss = v0 * v0 + v1 * v1;
            #pragma unroll
            for (int off = 32; off > 0; off >>= 1) ss += __shfl_down(ss, off);
            if (lane == 0) {
                xinv[row] = 1.0f / fmaxf(sqrtf(ss), 1e-12f);
                float fa = powf(1.5f, factor[row] * (1.0f / 12.0f)) * 0.5f;
                fa_out[row] = fa;
                thr_out[row] = (float)M_PI - fa;
            }
        }
        return;
    }

    const int k  = blockIdx.x / NCB;
    const int cb = blockIdx.x - k * NCB;
    const int o0 = cb * 64;
    const int col = tid & 63, seg = tid >> 6;
    const int c   = tid >> 2, sub = tid & 3;
    const int wn_ = c >> 5, n2_ = (c >> 4) & 1, l15_ = c & 15;

    float sqacc = 0.0f;
    #pragma unroll
    for (int h = 0; h < 2; h++) {
        // stage f-half h: 64 rows x 64 cols fp32, coalesced
        #pragma unroll
        for (int it = 0; it < 4; it++) {
            int idx = it * 256 + tid;      // float4 idx 0..1023
            int f = idx >> 4, c4 = idx & 15;
            int o = o0 + c4 * 4;
            float4 v = make_float4(0.f, 0.f, 0.f, 0.f);
            if (o < NOUT)
                v = *(const float4*)(W + (size_t)(k * FIN + h * 64 + f) * NOUT + o);
            *(float4*)(s + f * 64 + c4 * 4) = v;
        }
        __syncthreads();
        // partial sumsq (16 f per thread)
        float ss = 0.0f;
        #pragma unroll
        for (int f2 = 0; f2 < 16; f2++) {
            float x = s[(seg * 16 + f2) * 64 + col];
            ss = fmaf(x, x, ss);
        }
        sqacc += ss;
        // pack this half UNSCALED
        #pragma unroll
        for (int i = 0; i < 2; i++) {
            int tcl = sub * 2 + i;          // 0..7
            int tcg = h * 8 + tcl;          // 0..15
            int kk = tcg >> 2, qq = tcg & 3;
            int fb = tcl * 8;               // LDS f-row base
            uint4 u;
            u.x = packbf(s[(fb + 0) * 64 + c], s[(fb + 1) * 64 + c]);
            u.y = packbf(s[(fb + 2) * 64 + c], s[(fb + 3) * 64 + c]);
            u.z = packbf(s[(fb + 4) * 64 + c], s[(fb + 5) * 64 + c]);
            u.w = packbf(s[(fb + 6) * 64 + c], s[(fb + 7) * 64 + c]);
            wout[wn_ * 512 + n2_ * 256 + kk * 64 + qq * 16 + l15_] = u;
        }
        __syncthreads();   // pack reads done before restage / before copy-out
    }
    sq2[tid] = sqacc;
    __syncthreads();
    if (tid < 64)
        wis[tid] = 1.0f / fmaxf(sqrtf(sq2[tid] + sq2[tid + 64] + sq2[tid + 128] + sq2[tid + 192]), 1e-12f);
    __syncthreads();

    // scaled coalesced copy-out
    unsigned char* dst = Wbf + ((size_t)k * NCB + cb) * 16384;
    #pragma unroll
    for (int i = 0; i < 4; i++) {
        int idx = i * 256 + tid;
        int ccol = ((idx >> 9) << 5) + (((idx >> 8) & 1) << 4) + (idx & 15);
        float wi = wis[ccol];
        uint4 u = wout[idx];
        uint4 r;
        r.x = scale2(u.x, wi);
        r.y = scale2(u.y, wi);
        r.z = scale2(u.z, wi);
        r.w = scale2(u.w, wi);
        *(uint4*)(dst + (size_t)idx * 16) = r;
    }
}

// ---------------------------------------------------------------------------
// Kernel B v5: 256 threads = 4 waves, 1m x 4n, wave tile 64 rows x 16 cols,
// block tile 64x64. Rationale: 64-row wave tiles give 4 MFMAs per B-frag-KB
// (2x r2) and all 4 waves have distinct wn -> B LDS redundancy 1x. The r4
// failure was the VGPR cap: 512-thread blocks @ launch_bounds(...,2) cap the
// unified file at 128 regs; af[4][4]=64 spilled wholesale (WRITE_SIZE 177MB).
// 256-thread blocks @ launch_bounds(256,2) -> budget 256 regs, 2 independent
// blocks/CU (cross-block overlap of barrier phases). 3-buffer counted-vmcnt
// pipeline from r2 kept; 4 async16/issue -> steady-state vmcnt(4).
__global__ __launch_bounds__(256, 2) void gemm_mx(
    const float* __restrict__ X, const unsigned char* __restrict__ Wbf,
    const int* __restrict__ label, const float* __restrict__ xinv,
    float2* __restrict__ partial, float* __restrict__ cosl) {

    __shared__ union {
        short xs[64 * LDX];      // 17408 B, X staging (64 rows)
        short bb[3][8192];       // 3 x 16 KB B buffers = 49152 B
        float2 ms[64][4];        // 2 KB slab-stats combine (after loop only)
    } u;

    const int tid  = threadIdx.x;
    const int lane = tid & 63;
    const int w    = tid >> 6;     // 0..3 == n-slot (16 cols each)
    const int l15  = lane & 15;
    const int q    = lane >> 4;

    // XCD-aware decode: ids {group*128 + y*8 + xcd} -> cb = group*8 + xcd
    const int id    = blockIdx.x;
    const int group = id >> 7;
    const int sub   = id & 127;
    const int cb    = group * 8 + (sub & 7);
    const int y     = sub >> 3;            // 0..15
    if (cb >= NCB) return;
    const int r0 = y * 64;
    const int o0 = cb * 64;

    // ---- stage X tile (64 rows) as bf16 with xinv folded ----
    #pragma unroll
    for (int it = 0; it < 8; it++) {
        int idx = it * 256 + tid;      // float4 index 0..2047
        int row = idx >> 5;
        int c4  = idx & 31;
        const float4 v = *(const float4*)(X + (size_t)(r0 + row) * FIN + c4 * 4);
        float xi = xinv[r0 + row];
        uint2 p;
        p.x = packbf(v.x * xi, v.y * xi);
        p.y = packbf(v.z * xi, v.w * xi);
        *(uint2*)(u.xs + row * LDX + c4 * 4) = p;
    }
    __syncthreads();

    // A fragments: 4 m-tiles (rows 0..63 of the block) x 4 kk
    short8 af[4][4];
    #pragma unroll
    for (int mt = 0; mt < 4; mt++)
        #pragma unroll
        for (int kk = 0; kk < 4; kk++)
            af[mt][kk] = *(const short8*)(u.xs + (mt * 16 + l15) * LDX + kk * 32 + q * 8);
    __syncthreads();   // X area now reusable as B buffers

    // per-step B staging: 16 KB; wave w loads 4 KB (4 async16 calls)
    auto issue = [&](int k, short* d) {
        const unsigned char* g = Wbf + ((size_t)k * NCB + cb) * 16384
                                 + (size_t)w * 4096 + (size_t)lane * 16;
        short* dw = d + w * 2048;
        async16(g, dw);
        async16(g + 1024, dw + 512);
        async16(g + 2048, dw + 1024);
        async16(g + 3072, dw + 1536);
    };

    short* rd = u.bb[0];   // holds loads(k)
    short* nx = u.bb[1];   // holds loads(k+1), in flight
    short* wr = u.bb[2];   // free; receives loads(k+2)

    issue(0, rd);
    issue(1, nx);

    floatx4 maxv[4];
    #pragma unroll
    for (int mt = 0; mt < 4; mt++)
        #pragma unroll
        for (int r = 0; r < 4; r++)
            maxv[mt][r] = -INFINITY;

    const int wboff = w * 2048 + lane * 8;   // wave's 16-col slab

    for (int k = 0; k < NK; k++) {
        // counted wait: my loads(k) (4 calls) done; loads(k+1) stay in flight
        if (k == NK - 1) {
            asm volatile("s_waitcnt vmcnt(0)" ::: "memory");
        } else {
            asm volatile("s_waitcnt vmcnt(4)" ::: "memory");
        }
        __builtin_amdgcn_s_barrier();
        if (k < NK - 2) issue(k + 2, wr);

        const short* wt = rd + wboff;

        floatx4 acc[4];
        #pragma unroll
        for (int mt = 0; mt < 4; mt++)
            acc[mt] = (floatx4){0.f, 0.f, 0.f, 0.f};
        #pragma unroll
        for (int kk = 0; kk < 4; kk++) {
            short8 bf = *(const short8*)(wt + kk * 512);
            #pragma unroll
            for (int mt = 0; mt < 4; mt++)
                acc[mt] = __builtin_amdgcn_mfma_f32_16x16x32_bf16(
                    af[mt][kk], bf, acc[mt], 0, 0, 0);
        }
        #pragma unroll
        for (int mt = 0; mt < 4; mt++)
            #pragma unroll
            for (int r = 0; r < 4; r++)
                maxv[mt][r] = fmaxf(maxv[mt][r], acc[mt][r]);

        // rotate buffers: rd <- nx <- wr <- old rd
        short* t = rd; rd = nx; nx = wr; wr = t;
    }

    // ---- epilogue: per-slab stats (16 cols), then LDS combine of 4 slabs ----
    __syncthreads();   // all B-buffer ds_reads done; LDS reusable as ms[][]

    #pragma unroll
    for (int mt = 0; mt < 4; mt++) {
        #pragma unroll
        for (int rr = 0; rr < 4; rr++) {
            int rloc = mt * 16 + q * 4 + rr;    // 0..63
            int row = r0 + rloc;
            int lb = label[row];
            float m = -1e30f, sum = 0.f;
            int o = o0 + w * 16 + l15;
            if (o < NOUT) {
                float cc = maxv[mt][rr];
                if (o == lb) {
                    cosl[row] = cc;   // unique writer grid-wide
                } else {
                    float l = 64.0f * fminf(fmaxf(cc, -1.0f + 1e-6f), 1.0f - 1e-6f);
                    sum = __expf(l - 64.0f);
                    m = l;
                }
            }
            #pragma unroll
            for (int off = 1; off <= 8; off <<= 1) {
                sum += __shfl_xor(sum, off);
                m = fmaxf(m, __shfl_xor(m, off));
            }
            if (l15 == 0)
                u.ms[rloc][w] = make_float2(m, sum);
        }
    }
    __syncthreads();

    if (tid < 64) {
        float2 a = u.ms[tid][0], b = u.ms[tid][1];
        float2 c2 = u.ms[tid][2], d = u.ms[tid][3];
        float m = fmaxf(fmaxf(a.x, b.x), fmaxf(c2.x, d.x));
        float s = (a.y + b.y) + (c2.y + d.y);
        partial[(size_t)(r0 + tid) * NPARTM + cb] = make_float2(m, s);
    }
}

// ---------------------------------------------------------------------------
// Fallback GEMM (used when ws_size can't hold Wbf). Stride NPART partials.
__global__ __launch_bounds__(256, 2) void gemm_stats(
    const float* __restrict__ X, const float* __restrict__ W,
    const int* __restrict__ label, const float* __restrict__ xinv,
    float2* __restrict__ partial, float* __restrict__ cosl) {

    __shared__ short xs[128 * LDX];
    __shared__ short wt[128 * LDX];
    __shared__ float sqs[128][2];

    const int tid  = threadIdx.x;
    const int lane = tid & 63;
    const int w    = tid >> 6;
    const int l15  = lane & 15;
    const int q    = lane >> 4;
    const int wm   = w & 1;
    const int wn   = w >> 1;

    const int id    = blockIdx.x;
    const int group = id >> 6;
    const int sub   = id & 63;
    const int jb    = group * 8 + (sub & 7);
    const int y     = sub >> 3;
    if (jb >= NBLK) return;
    const int r0 = y * 128;
    const int o0 = jb * 128;

    #pragma unroll
    for (int it = 0; it < 16; it++) {
        int idx = it * 256 + tid;
        int row = idx >> 5;
        int c4  = idx & 31;
        const float4 v = *(const float4*)(X + (size_t)(r0 + row) * FIN + c4 * 4);
        uint2 p;
        p.x = packbf(v.x, v.y);
        p.y = packbf(v.z, v.w);
        *(uint2*)(xs + row * LDX + c4 * 4) = p;
    }

    const int st_o = (w & 1) * 64 + lane;
    const int st_f = (w >> 1) * 64;
    const int st_h = w >> 1;
    const int go   = o0 + st_o;
    const bool ov  = go < NOUT;

    float rw[64];
    {
        const float* Wp = W + (size_t)st_f * NOUT + go;
        #pragma unroll
        for (int g = 0; g < 16; g++)
            #pragma unroll
            for (int cc = 0; cc < 4; cc++)
                rw[g * 4 + cc] = ov ? Wp[(size_t)(g * 4 + cc) * NOUT] : 0.0f;
    }
    __syncthreads();

    short8 af[4][4];
    #pragma unroll
    for (int mt = 0; mt < 4; mt++)
        #pragma unroll
        for (int kk = 0; kk < 4; kk++)
            af[mt][kk] = *(const short8*)(xs + (wm * 64 + mt * 16 + l15) * LDX + kk * 32 + q * 8);

    floatx4 maxv[4][4];
    #pragma unroll
    for (int mt = 0; mt < 4; mt++)
        #pragma unroll
        for (int nt = 0; nt < 4; nt++)
            #pragma unroll
            for (int r = 0; r < 4; r++)
                maxv[mt][nt][r] = -INFINITY;

    for (int k = 0; k < NK; k++) {
        float sq = 0.0f;
        uint2 pk[16];
        #pragma unroll
        for (int g = 0; g < 16; g++) {
            float a0 = rw[g * 4 + 0], a1 = rw[g * 4 + 1];
            float a2 = rw[g * 4 + 2], a3 = rw[g * 4 + 3];
            sq = fmaf(a0, a0, sq); sq = fmaf(a1, a1, sq);
            sq = fmaf(a2, a2, sq); sq = fmaf(a3, a3, sq);
            pk[g].x = packbf(a0, a1);
            pk[g].y = packbf(a2, a3);
        }
        __syncthreads();
        #pragma unroll
        for (int g = 0; g < 16; g++)
            *(uint2*)(wt + st_o * LDX + st_f + g * 4) = pk[g];
        sqs[st_o][st_h] = sq;
        __syncthreads();

        if (k < NK - 1) {
            const float* Wn = W + ((size_t)(k + 1) * FIN + st_f) * NOUT + go;
            #pragma unroll
            for (int g = 0; g < 16; g++)
                #pragma unroll
                for (int cc = 0; cc < 4; cc++)
                    rw[g * 4 + cc] = ov ? Wn[(size_t)(g * 4 + cc) * NOUT] : 0.0f;
        }

        float wv[4];
        #pragma unroll
        for (int nt = 0; nt < 4; nt++) {
            int colx = wn * 64 + nt * 16 + l15;
            wv[nt] = 1.0f / fmaxf(sqrtf(sqs[colx][0] + sqs[colx][1]), 1e-12f);
        }

        #pragma unroll
        for (int h = 0; h < 2; h++) {
            floatx4 acc[4][2];
            #pragma unroll
            for (int mt = 0; mt < 4; mt++) {
                acc[mt][0] = (floatx4){0.f, 0.f, 0.f, 0.f};
                acc[mt][1] = (floatx4){0.f, 0.f, 0.f, 0.f};
            }
            #pragma unroll
            for (int kk = 0; kk < 4; kk++) {
                short8 bf0 = *(const short8*)(wt + (wn * 64 + (h * 2 + 0) * 16 + l15) * LDX + kk * 32 + q * 8);
                short8 bf1 = *(const short8*)(wt + (wn * 64 + (h * 2 + 1) * 16 + l15) * LDX + kk * 32 + q * 8);
                #pragma unroll
                for (int mt = 0; mt < 4; mt++) {
                    acc[mt][0] = __builtin_amdgcn_mfma_f32_16x16x32_bf16(af[mt][kk], bf0, acc[mt][0], 0, 0, 0);
                    acc[mt][1] = __builtin_amdgcn_mfma_f32_16x16x32_bf16(af[mt][kk], bf1, acc[mt][1], 0, 0, 0);
                }
            }
            #pragma unroll
            for (int mt = 0; mt < 4; mt++)
                #pragma unroll
                for (int n2 = 0; n2 < 2; n2++)
                    #pragma unroll
                    for (int r = 0; r < 4; r++)
                        maxv[mt][h * 2 + n2][r] =
                            fmaxf(maxv[mt][h * 2 + n2][r], acc[mt][n2][r] * wv[h * 2 + n2]);
        }
    }

    #pragma unroll
    for (int mt = 0; mt < 4; mt++) {
        #pragma unroll
        for (int rr = 0; rr < 4; rr++) {
            int row = r0 + wm * 64 + mt * 16 + q * 4 + rr;
            float xi = xinv[row];
            int lb = label[row];
            float m = -1e30f, sum = 0.f;
            #pragma unroll
            for (int nt = 0; nt < 4; nt++) {
                int o = o0 + wn * 64 + nt * 16 + l15;
                if (o < NOUT) {
                    float cc = maxv[mt][nt][rr] * xi;
                    if (o == lb) {
                        cosl[row] = cc;
                    } else {
                        float l = 64.0f * fminf(fmaxf(cc, -1.0f + 1e-6f), 1.0f - 1e-6f);
                        sum += __expf(l - 64.0f);
                        m = fmaxf(m, l);
                    }
                }
            }
            #pragma unroll
            for (int off = 1; off <= 8; off <<= 1) {
                sum += __shfl_xor(sum, off);
                m = fmaxf(m, __shfl_xor(m, off));
            }
            if (l15 == 0) {
                partial[(size_t)row * NPART + jb * 4 + wn * 2 + 0] = make_float2(m, sum);
                partial[(size_t)row * NPART + jb * 4 + wn * 2 + 1] = make_float2(-1e30f, 0.f);
            }
        }
    }
}

// ---------------------------------------------------------------------------
// Kernel C1: per-row combine (fixed-ref: plain sum+max) + margin. np = stride.
__global__ void finalize_rows(const float2* __restrict__ partial, const float* __restrict__ cosl,
                              const float* __restrict__ fa, const float* __restrict__ thr,
                              float2* __restrict__ rowres, int np) {
    int w = threadIdx.x >> 6;
    int lane = threadIdx.x & 63;
    int b = blockIdx.x * 4 + w;
    float m = -1e30f, s = 0.0f;
    for (int j = lane; j < np; j += 64) {
        float2 p = partial[(size_t)b * np + j];
        s += p.y;
        m = fmaxf(m, p.x);
    }
    #pragma unroll
    for (int off = 1; off < 64; off <<= 1) {
        s += __shfl_xor(s, off);
        m = fmaxf(m, __shfl_xor(m, off));
    }
    if (lane == 0) {
        float c = fminf(fmaxf(cosl[b], -1.0f + 1e-6f), 1.0f - 1e-6f);
        float theta = acosf(c);
        float ll = (theta > thr[b]) ? 64.0f * c : 64.0f * cosf(theta + fa[b]);
        float S = s + __expf(ll - 64.0f);
        float loss = 64.0f + logf(S) - ll;
        rowres[b] = make_float2(loss, (ll > m) ? 100.0f : 0.0f);
    }
}

// Kernel C2: deterministic tree reduce of 1024 rows -> 2 scalars.
__global__ void finalize_sum(const float2* __restrict__ rowres, float* __restrict__ out) {
    __shared__ float sl[1024];
    __shared__ float sc[1024];
    int b = threadIdx.x;
    float2 v = rowres[b];
    sl[b] = v.x;
    sc[b] = v.y;
    __syncthreads();
    for (int st = 512; st > 0; st >>= 1) {
        if (b < st) { sl[b] += sl[b + st]; sc[b] += sc[b + st]; }
        __syncthreads();
    }
    if (b == 0) {
        out[0] = sl[0] * (1.0f / 1024.0f);
        out[1] = sc[0] * (1.0f / 1024.0f);
    }
}

// ---------------------------------------------------------------------------
extern "C" void kernel_launch(void* const* d_in, const int* in_sizes, int n_in,
                              void* d_out, int out_size, void* d_ws, size_t ws_size,
                              hipStream_t stream) {
    const float* X      = (const float*)d_in[0];
    const float* factor = (const float*)d_in[1];
    const int*   label  = (const int*)d_in[2];
    const float* W      = (const float*)d_in[3];
    float* out = (float*)d_out;
    float* ws  = (float*)d_ws;

    float*  xinv = ws;                        // 1024
    float*  fa   = ws + 1024;                 // 1024
    float*  thr  = ws + 2048;                 // 1024
    float*  cosl = ws + 3072;                 // 1024
    float2* rowres = (float2*)(ws + 4096);    // 1024 float2
    float2* partial = (float2*)(ws + 6144);   // 1024 x 316 float2 max (~2.6 MB)
    unsigned char* Wbf = (unsigned char*)d_ws + 4 * 1024 * 1024;  // 41.4 MB

    const size_t wbf_bytes = (size_t)NK * NCB * 16384;
    const size_t need = 4ull * 1024 * 1024 + wbf_bytes;

    if (ws_size >= need) {
        wconv<<<NK * NCB + 16, 256, 0, stream>>>(W, Wbf, X, factor, xinv, fa, thr);
        gemm_mx<<<2560, 256, 0, stream>>>(X, Wbf, label, xinv, partial, cosl);
        finalize_rows<<<BB / 4, 256, 0, stream>>>(partial, cosl, fa, thr, rowres, NPARTM);
    } else {
        rowprep<<<BB, 64, 0, stream>>>(X, factor, xinv, fa, thr);
        gemm_stats<<<640, 256, 0, stream>>>(X, W, label, xinv, partial, cosl);
        finalize_rows<<<BB / 4, 256, 0, stream>>>(partial, cosl, fa, thr, rowres, NPART);
    }
    finalize_sum<<<1, BB, 0, stream>>>(rowres, out);
}

// Round 6
// 274.672 us; speedup vs baseline: 1.0255x; 1.0007x over previous
//
#include <hip/hip_runtime.h>
#include <hip/hip_bf16.h>
#include <math.h>

#define BB    1024
#define FIN   128
#define NOUT  10000
#define NBLK  79          // 128-col strips (fallback path)
#define NCB   158         // 64-col regions (Wbf layout)
#define NK    16
#define NPART (NCB * 2)   // fallback-path partial stride = 316
#define NPARTM NCB        // main-path partial stride = 158 (post LDS-combine)
#define LDX   136         // LDS stride (shorts) for the X tile

typedef __attribute__((ext_vector_type(8))) short short8;
typedef __attribute__((ext_vector_type(4))) float floatx4;

__device__ __forceinline__ unsigned packbf(float a, float b) {
    __hip_bfloat162 h = __float22bfloat162_rn(make_float2(a, b));
    union { __hip_bfloat162 h2; unsigned u; } v;
    v.h2 = h;
    return v.u;
}

// unpack bf16 pair, scale, repack
__device__ __forceinline__ unsigned scale2(unsigned p, float wi) {
    float lo = __uint_as_float(p << 16) * wi;
    float hi = __uint_as_float(p & 0xffff0000u) * wi;
    return packbf(lo, hi);
}

// async global->LDS, 16B per lane; LDS dest = wave-uniform base + lane*16.
__device__ __forceinline__ void async16(const void* g, void* l) {
    __builtin_amdgcn_global_load_lds(
        (const __attribute__((address_space(1))) unsigned int*)g,
        (__attribute__((address_space(3))) unsigned int*)l, 16, 0, 0);
}

// ---------------------------------------------------------------------------
// Kernel A (fallback path only)
__global__ void rowprep(const float* __restrict__ X, const float* __restrict__ factor,
                        float* __restrict__ xinv, float* __restrict__ fa_out,
                        float* __restrict__ thr_out) {
    int b = blockIdx.x;
    int lane = threadIdx.x;
    float v0 = X[b * FIN + lane];
    float v1 = X[b * FIN + 64 + lane];
    float s = v0 * v0 + v1 * v1;
    #pragma unroll
    for (int off = 32; off > 0; off >>= 1) s += __shfl_down(s, off);
    if (lane == 0) {
        xinv[b] = 1.0f / fmaxf(sqrtf(s), 1e-12f);
        float fa = powf(1.5f, factor[b] * (1.0f / 12.0f)) * 0.5f;
        fa_out[b] = fa;
        thr_out[b] = (float)M_PI - fa;
    }
}

// ---------------------------------------------------------------------------
// Kernel W v3 (proven): f-half staging (16 KB) + deferred winv scale at
// copy-out. LDS ~33.5 KB -> 4 blocks/CU. Wbf layout: per (k, cb64) 16 KB
// region [s(4 col-slabs of 16)][kk(4)][lane=q*16+l15][16B], holding
// bf16(W * winv), o = cb*64 + s*16 + l15, f=(kk*4+q)*8..+7.
__global__ __launch_bounds__(256) void wconv(
    const float* __restrict__ W, unsigned char* __restrict__ Wbf,
    const float* __restrict__ X, const float* __restrict__ factor,
    float* __restrict__ xinv, float* __restrict__ fa_out, float* __restrict__ thr_out) {

    __shared__ float s[64 * 64];    // 16 KB: one f-half, [f][c] fp32
    __shared__ uint4 wout[1024];    // 16 KB packed (unscaled bf16)
    __shared__ float sq2[256];
    __shared__ float wis[64];

    const int tid = threadIdx.x;

    // rowprep tail blocks
    if (blockIdx.x >= NK * NCB) {
        int rb = blockIdx.x - NK * NCB;   // 0..15
        int w4 = tid >> 6, lane = tid & 63;
        for (int i = w4; i < 64; i += 4) {
            int row = rb * 64 + i;
            float v0 = X[row * FIN + lane];
            float v1 = X[row * FIN + 64 + lane];
            float ss = v0 * v0 + v1 * v1;
            #pragma unroll
            for (int off = 32; off > 0; off >>= 1) ss += __shfl_down(ss, off);
            if (lane == 0) {
                xinv[row] = 1.0f / fmaxf(sqrtf(ss), 1e-12f);
                float fa = powf(1.5f, factor[row] * (1.0f / 12.0f)) * 0.5f;
                fa_out[row] = fa;
                thr_out[row] = (float)M_PI - fa;
            }
        }
        return;
    }

    const int k  = blockIdx.x / NCB;
    const int cb = blockIdx.x - k * NCB;
    const int o0 = cb * 64;
    const int col = tid & 63, seg = tid >> 6;
    const int c   = tid >> 2, sub = tid & 3;
    const int wn_ = c >> 5, n2_ = (c >> 4) & 1, l15_ = c & 15;

    float sqacc = 0.0f;
    #pragma unroll
    for (int h = 0; h < 2; h++) {
        // stage f-half h: 64 rows x 64 cols fp32, coalesced
        #pragma unroll
        for (int it = 0; it < 4; it++) {
            int idx = it * 256 + tid;      // float4 idx 0..1023
            int f = idx >> 4, c4 = idx & 15;
            int o = o0 + c4 * 4;
            float4 v = make_float4(0.f, 0.f, 0.f, 0.f);
            if (o < NOUT)
                v = *(const float4*)(W + (size_t)(k * FIN + h * 64 + f) * NOUT + o);
            *(float4*)(s + f * 64 + c4 * 4) = v;
        }
        __syncthreads();
        // partial sumsq (16 f per thread)
        float ss = 0.0f;
        #pragma unroll
        for (int f2 = 0; f2 < 16; f2++) {
            float x = s[(seg * 16 + f2) * 64 + col];
            ss = fmaf(x, x, ss);
        }
        sqacc += ss;
        // pack this half UNSCALED
        #pragma unroll
        for (int i = 0; i < 2; i++) {
            int tcl = sub * 2 + i;          // 0..7
            int tcg = h * 8 + tcl;          // 0..15
            int kk = tcg >> 2, qq = tcg & 3;
            int fb = tcl * 8;               // LDS f-row base
            uint4 u;
            u.x = packbf(s[(fb + 0) * 64 + c], s[(fb + 1) * 64 + c]);
            u.y = packbf(s[(fb + 2) * 64 + c], s[(fb + 3) * 64 + c]);
            u.z = packbf(s[(fb + 4) * 64 + c], s[(fb + 5) * 64 + c]);
            u.w = packbf(s[(fb + 6) * 64 + c], s[(fb + 7) * 64 + c]);
            wout[wn_ * 512 + n2_ * 256 + kk * 64 + qq * 16 + l15_] = u;
        }
        __syncthreads();   // pack reads done before restage / before copy-out
    }
    sq2[tid] = sqacc;
    __syncthreads();
    if (tid < 64)
        wis[tid] = 1.0f / fmaxf(sqrtf(sq2[tid] + sq2[tid + 64] + sq2[tid + 128] + sq2[tid + 192]), 1e-12f);
    __syncthreads();

    // scaled coalesced copy-out
    unsigned char* dst = Wbf + ((size_t)k * NCB + cb) * 16384;
    #pragma unroll
    for (int i = 0; i < 4; i++) {
        int idx = i * 256 + tid;
        int ccol = ((idx >> 9) << 5) + (((idx >> 8) & 1) << 4) + (idx & 15);
        float wi = wis[ccol];
        uint4 u = wout[idx];
        uint4 r;
        r.x = scale2(u.x, wi);
        r.y = scale2(u.y, wi);
        r.z = scale2(u.z, wi);
        r.w = scale2(u.w, wi);
        *(uint4*)(dst + (size_t)idx * 16) = r;
    }
}

// ---------------------------------------------------------------------------
// Kernel B v6: IDENTICAL body to v5 (256 thr, 4 waves 1m x 4n, wave tile
// 64x16, block tile 64x64, 3-buffer counted-vmcnt pipeline, LDS slab-combine
// epilogue — correctness proven r4/r5, absmax 0.0). ONE change: register
// budget requested via explicit amdgpu_waves_per_eu(2,2) instead of
// launch_bounds 2nd arg. r1/r4/r5 all compiled to a 128-VGPR budget and
// spilled af[4][4] (WRITE_SIZE 177 MB, ~270 B/thread scratch); demand here
// is ~130 regs, which fits the 256-reg budget of 2 waves/EU. If this still
// reports VGPR 128 + WRITE ~177 MB, the allocator won't exceed 128 on this
// body: revert to the r2 gemm permanently.
__global__ __attribute__((amdgpu_waves_per_eu(2, 2))) __launch_bounds__(256)
void gemm_mx(
    const float* __restrict__ X, const unsigned char* __restrict__ Wbf,
    const int* __restrict__ label, const float* __restrict__ xinv,
    float2* __restrict__ partial, float* __restrict__ cosl) {

    __shared__ union {
        short xs[64 * LDX];      // 17408 B, X staging (64 rows)
        short bb[3][8192];       // 3 x 16 KB B buffers = 49152 B
        float2 ms[64][4];        // 2 KB slab-stats combine (after loop only)
    } u;

    const int tid  = threadIdx.x;
    const int lane = tid & 63;
    const int w    = tid >> 6;     // 0..3 == n-slot (16 cols each)
    const int l15  = lane & 15;
    const int q    = lane >> 4;

    // XCD-aware decode: ids {group*128 + y*8 + xcd} -> cb = group*8 + xcd
    const int id    = blockIdx.x;
    const int group = id >> 7;
    const int sub   = id & 127;
    const int cb    = group * 8 + (sub & 7);
    const int y     = sub >> 3;            // 0..15
    if (cb >= NCB) return;
    const int r0 = y * 64;
    const int o0 = cb * 64;

    // ---- stage X tile (64 rows) as bf16 with xinv folded ----
    #pragma unroll
    for (int it = 0; it < 8; it++) {
        int idx = it * 256 + tid;      // float4 index 0..2047
        int row = idx >> 5;
        int c4  = idx & 31;
        const float4 v = *(const float4*)(X + (size_t)(r0 + row) * FIN + c4 * 4);
        float xi = xinv[r0 + row];
        uint2 p;
        p.x = packbf(v.x * xi, v.y * xi);
        p.y = packbf(v.z * xi, v.w * xi);
        *(uint2*)(u.xs + row * LDX + c4 * 4) = p;
    }
    __syncthreads();

    // A fragments: 4 m-tiles (rows 0..63 of the block) x 4 kk
    short8 af[4][4];
    #pragma unroll
    for (int mt = 0; mt < 4; mt++)
        #pragma unroll
        for (int kk = 0; kk < 4; kk++)
            af[mt][kk] = *(const short8*)(u.xs + (mt * 16 + l15) * LDX + kk * 32 + q * 8);
    __syncthreads();   // X area now reusable as B buffers

    // per-step B staging: 16 KB; wave w loads 4 KB (4 async16 calls)
    auto issue = [&](int k, short* d) {
        const unsigned char* g = Wbf + ((size_t)k * NCB + cb) * 16384
                                 + (size_t)w * 4096 + (size_t)lane * 16;
        short* dw = d + w * 2048;
        async16(g, dw);
        async16(g + 1024, dw + 512);
        async16(g + 2048, dw + 1024);
        async16(g + 3072, dw + 1536);
    };

    short* rd = u.bb[0];   // holds loads(k)
    short* nx = u.bb[1];   // holds loads(k+1), in flight
    short* wr = u.bb[2];   // free; receives loads(k+2)

    issue(0, rd);
    issue(1, nx);

    floatx4 maxv[4];
    #pragma unroll
    for (int mt = 0; mt < 4; mt++)
        #pragma unroll
        for (int r = 0; r < 4; r++)
            maxv[mt][r] = -INFINITY;

    const int wboff = w * 2048 + lane * 8;   // wave's 16-col slab

    for (int k = 0; k < NK; k++) {
        // counted wait: my loads(k) (4 calls) done; loads(k+1) stay in flight
        if (k == NK - 1) {
            asm volatile("s_waitcnt vmcnt(0)" ::: "memory");
        } else {
            asm volatile("s_waitcnt vmcnt(4)" ::: "memory");
        }
        __builtin_amdgcn_s_barrier();
        if (k < NK - 2) issue(k + 2, wr);

        const short* wt = rd + wboff;

        floatx4 acc[4];
        #pragma unroll
        for (int mt = 0; mt < 4; mt++)
            acc[mt] = (floatx4){0.f, 0.f, 0.f, 0.f};
        #pragma unroll
        for (int kk = 0; kk < 4; kk++) {
            short8 bf = *(const short8*)(wt + kk * 512);
            #pragma unroll
            for (int mt = 0; mt < 4; mt++)
                acc[mt] = __builtin_amdgcn_mfma_f32_16x16x32_bf16(
                    af[mt][kk], bf, acc[mt], 0, 0, 0);
        }
        #pragma unroll
        for (int mt = 0; mt < 4; mt++)
            #pragma unroll
            for (int r = 0; r < 4; r++)
                maxv[mt][r] = fmaxf(maxv[mt][r], acc[mt][r]);

        // rotate buffers: rd <- nx <- wr <- old rd
        short* t = rd; rd = nx; nx = wr; wr = t;
    }

    // ---- epilogue: per-slab stats (16 cols), then LDS combine of 4 slabs ----
    __syncthreads();   // all B-buffer ds_reads done; LDS reusable as ms[][]

    #pragma unroll
    for (int mt = 0; mt < 4; mt++) {
        #pragma unroll
        for (int rr = 0; rr < 4; rr++) {
            int rloc = mt * 16 + q * 4 + rr;    // 0..63
            int row = r0 + rloc;
            int lb = label[row];
            float m = -1e30f, sum = 0.f;
            int o = o0 + w * 16 + l15;
            if (o < NOUT) {
                float cc = maxv[mt][rr];
                if (o == lb) {
                    cosl[row] = cc;   // unique writer grid-wide
                } else {
                    float l = 64.0f * fminf(fmaxf(cc, -1.0f + 1e-6f), 1.0f - 1e-6f);
                    sum = __expf(l - 64.0f);
                    m = l;
                }
            }
            #pragma unroll
            for (int off = 1; off <= 8; off <<= 1) {
                sum += __shfl_xor(sum, off);
                m = fmaxf(m, __shfl_xor(m, off));
            }
            if (l15 == 0)
                u.ms[rloc][w] = make_float2(m, sum);
        }
    }
    __syncthreads();

    if (tid < 64) {
        float2 a = u.ms[tid][0], b = u.ms[tid][1];
        float2 c2 = u.ms[tid][2], d = u.ms[tid][3];
        float m = fmaxf(fmaxf(a.x, b.x), fmaxf(c2.x, d.x));
        float s = (a.y + b.y) + (c2.y + d.y);
        partial[(size_t)(r0 + tid) * NPARTM + cb] = make_float2(m, s);
    }
}

// ---------------------------------------------------------------------------
// Fallback GEMM (used when ws_size can't hold Wbf). Stride NPART partials.
__global__ __launch_bounds__(256, 2) void gemm_stats(
    const float* __restrict__ X, const float* __restrict__ W,
    const int* __restrict__ label, const float* __restrict__ xinv,
    float2* __restrict__ partial, float* __restrict__ cosl) {

    __shared__ short xs[128 * LDX];
    __shared__ short wt[128 * LDX];
    __shared__ float sqs[128][2];

    const int tid  = threadIdx.x;
    const int lane = tid & 63;
    const int w    = tid >> 6;
    const int l15  = lane & 15;
    const int q    = lane >> 4;
    const int wm   = w & 1;
    const int wn   = w >> 1;

    const int id    = blockIdx.x;
    const int group = id >> 6;
    const int sub   = id & 63;
    const int jb    = group * 8 + (sub & 7);
    const int y     = sub >> 3;
    if (jb >= NBLK) return;
    const int r0 = y * 128;
    const int o0 = jb * 128;

    #pragma unroll
    for (int it = 0; it < 16; it++) {
        int idx = it * 256 + tid;
        int row = idx >> 5;
        int c4  = idx & 31;
        const float4 v = *(const float4*)(X + (size_t)(r0 + row) * FIN + c4 * 4);
        uint2 p;
        p.x = packbf(v.x, v.y);
        p.y = packbf(v.z, v.w);
        *(uint2*)(xs + row * LDX + c4 * 4) = p;
    }

    const int st_o = (w & 1) * 64 + lane;
    const int st_f = (w >> 1) * 64;
    const int st_h = w >> 1;
    const int go   = o0 + st_o;
    const bool ov  = go < NOUT;

    float rw[64];
    {
        const float* Wp = W + (size_t)st_f * NOUT + go;
        #pragma unroll
        for (int g = 0; g < 16; g++)
            #pragma unroll
            for (int cc = 0; cc < 4; cc++)
                rw[g * 4 + cc] = ov ? Wp[(size_t)(g * 4 + cc) * NOUT] : 0.0f;
    }
    __syncthreads();

    short8 af[4][4];
    #pragma unroll
    for (int mt = 0; mt < 4; mt++)
        #pragma unroll
        for (int kk = 0; kk < 4; kk++)
            af[mt][kk] = *(const short8*)(xs + (wm * 64 + mt * 16 + l15) * LDX + kk * 32 + q * 8);

    floatx4 maxv[4][4];
    #pragma unroll
    for (int mt = 0; mt < 4; mt++)
        #pragma unroll
        for (int nt = 0; nt < 4; nt++)
            #pragma unroll
            for (int r = 0; r < 4; r++)
                maxv[mt][nt][r] = -INFINITY;

    for (int k = 0; k < NK; k++) {
        float sq = 0.0f;
        uint2 pk[16];
        #pragma unroll
        for (int g = 0; g < 16; g++) {
            float a0 = rw[g * 4 + 0], a1 = rw[g * 4 + 1];
            float a2 = rw[g * 4 + 2], a3 = rw[g * 4 + 3];
            sq = fmaf(a0, a0, sq); sq = fmaf(a1, a1, sq);
            sq = fmaf(a2, a2, sq); sq = fmaf(a3, a3, sq);
            pk[g].x = packbf(a0, a1);
            pk[g].y = packbf(a2, a3);
        }
        __syncthreads();
        #pragma unroll
        for (int g = 0; g < 16; g++)
            *(uint2*)(wt + st_o * LDX + st_f + g * 4) = pk[g];
        sqs[st_o][st_h] = sq;
        __syncthreads();

        if (k < NK - 1) {
            const float* Wn = W + ((size_t)(k + 1) * FIN + st_f) * NOUT + go;
            #pragma unroll
            for (int g = 0; g < 16; g++)
                #pragma unroll
                for (int cc = 0; cc < 4; cc++)
                    rw[g * 4 + cc] = ov ? Wn[(size_t)(g * 4 + cc) * NOUT] : 0.0f;
        }

        float wv[4];
        #pragma unroll
        for (int nt = 0; nt < 4; nt++) {
            int colx = wn * 64 + nt * 16 + l15;
            wv[nt] = 1.0f / fmaxf(sqrtf(sqs[colx][0] + sqs[colx][1]), 1e-12f);
        }

        #pragma unroll
        for (int h = 0; h < 2; h++) {
            floatx4 acc[4][2];
            #pragma unroll
            for (int mt = 0; mt < 4; mt++) {
                acc[mt][0] = (floatx4){0.f, 0.f, 0.f, 0.f};
                acc[mt][1] = (floatx4){0.f, 0.f, 0.f, 0.f};
            }
            #pragma unroll
            for (int kk = 0; kk < 4; kk++) {
                short8 bf0 = *(const short8*)(wt + (wn * 64 + (h * 2 + 0) * 16 + l15) * LDX + kk * 32 + q * 8);
                short8 bf1 = *(const short8*)(wt + (wn * 64 + (h * 2 + 1) * 16 + l15) * LDX + kk * 32 + q * 8);
                #pragma unroll
                for (int mt = 0; mt < 4; mt++) {
                    acc[mt][0] = __builtin_amdgcn_mfma_f32_16x16x32_bf16(af[mt][kk], bf0, acc[mt][0], 0, 0, 0);
                    acc[mt][1] = __builtin_amdgcn_mfma_f32_16x16x32_bf16(af[mt][kk], bf1, acc[mt][1], 0, 0, 0);
                }
            }
            #pragma unroll
            for (int mt = 0; mt < 4; mt++)
                #pragma unroll
                for (int n2 = 0; n2 < 2; n2++)
                    #pragma unroll
                    for (int r = 0; r < 4; r++)
                        maxv[mt][h * 2 + n2][r] =
                            fmaxf(maxv[mt][h * 2 + n2][r], acc[mt][n2][r] * wv[h * 2 + n2]);
        }
    }

    #pragma unroll
    for (int mt = 0; mt < 4; mt++) {
        #pragma unroll
        for (int rr = 0; rr < 4; rr++) {
            int row = r0 + wm * 64 + mt * 16 + q * 4 + rr;
            float xi = xinv[row];
            int lb = label[row];
            float m = -1e30f, sum = 0.f;
            #pragma unroll
            for (int nt = 0; nt < 4; nt++) {
                int o = o0 + wn * 64 + nt * 16 + l15;
                if (o < NOUT) {
                    float cc = maxv[mt][nt][rr] * xi;
                    if (o == lb) {
                        cosl[row] = cc;
                    } else {
                        float l = 64.0f * fminf(fmaxf(cc, -1.0f + 1e-6f), 1.0f - 1e-6f);
                        sum += __expf(l - 64.0f);
                        m = fmaxf(m, l);
                    }
                }
            }
            #pragma unroll
            for (int off = 1; off <= 8; off <<= 1) {
                sum += __shfl_xor(sum, off);
                m = fmaxf(m, __shfl_xor(m, off));
            }
            if (l15 == 0) {
                partial[(size_t)row * NPART + jb * 4 + wn * 2 + 0] = make_float2(m, sum);
                partial[(size_t)row * NPART + jb * 4 + wn * 2 + 1] = make_float2(-1e30f, 0.f);
            }
        }
    }
}

// ---------------------------------------------------------------------------
// Kernel C1: per-row combine (fixed-ref: plain sum+max) + margin. np = stride.
__global__ void finalize_rows(const float2* __restrict__ partial, const float* __restrict__ cosl,
                              const float* __restrict__ fa, const float* __restrict__ thr,
                              float2* __restrict__ rowres, int np) {
    int w = threadIdx.x >> 6;
    int lane = threadIdx.x & 63;
    int b = blockIdx.x * 4 + w;
    float m = -1e30f, s = 0.0f;
    for (int j = lane; j < np; j += 64) {
        float2 p = partial[(size_t)b * np + j];
        s += p.y;
        m = fmaxf(m, p.x);
    }
    #pragma unroll
    for (int off = 1; off < 64; off <<= 1) {
        s += __shfl_xor(s, off);
        m = fmaxf(m, __shfl_xor(m, off));
    }
    if (lane == 0) {
        float c = fminf(fmaxf(cosl[b], -1.0f + 1e-6f), 1.0f - 1e-6f);
        float theta = acosf(c);
        float ll = (theta > thr[b]) ? 64.0f * c : 64.0f * cosf(theta + fa[b]);
        float S = s + __expf(ll - 64.0f);
        float loss = 64.0f + logf(S) - ll;
        rowres[b] = make_float2(loss, (ll > m) ? 100.0f : 0.0f);
    }
}

// Kernel C2: deterministic tree reduce of 1024 rows -> 2 scalars.
__global__ void finalize_sum(const float2* __restrict__ rowres, float* __restrict__ out) {
    __shared__ float sl[1024];
    __shared__ float sc[1024];
    int b = threadIdx.x;
    float2 v = rowres[b];
    sl[b] = v.x;
    sc[b] = v.y;
    __syncthreads();
    for (int st = 512; st > 0; st >>= 1) {
        if (b < st) { sl[b] += sl[b + st]; sc[b] += sc[b + st]; }
        __syncthreads();
    }
    if (b == 0) {
        out[0] = sl[0] * (1.0f / 1024.0f);
        out[1] = sc[0] * (1.0f / 1024.0f);
    }
}

// ---------------------------------------------------------------------------
extern "C" void kernel_launch(void* const* d_in, const int* in_sizes, int n_in,
                              void* d_out, int out_size, void* d_ws, size_t ws_size,
                              hipStream_t stream) {
    const float* X      = (const float*)d_in[0];
    const float* factor = (const float*)d_in[1];
    const int*   label  = (const int*)d_in[2];
    const float* W      = (const float*)d_in[3];
    float* out = (float*)d_out;
    float* ws  = (float*)d_ws;

    float*  xinv = ws;                        // 1024
    float*  fa   = ws + 1024;                 // 1024
    float*  thr  = ws + 2048;                 // 1024
    float*  cosl = ws + 3072;                 // 1024
    float2* rowres = (float2*)(ws + 4096);    // 1024 float2
    float2* partial = (float2*)(ws + 6144);   // 1024 x 316 float2 max (~2.6 MB)
    unsigned char* Wbf = (unsigned char*)d_ws + 4 * 1024 * 1024;  // 41.4 MB

    const size_t wbf_bytes = (size_t)NK * NCB * 16384;
    const size_t need = 4ull * 1024 * 1024 + wbf_bytes;

    if (ws_size >= need) {
        wconv<<<NK * NCB + 16, 256, 0, stream>>>(W, Wbf, X, factor, xinv, fa, thr);
        gemm_mx<<<2560, 256, 0, stream>>>(X, Wbf, label, xinv, partial, cosl);
        finalize_rows<<<BB / 4, 256, 0, stream>>>(partial, cosl, fa, thr, rowres, NPARTM);
    } else {
        rowprep<<<BB, 64, 0, stream>>>(X, factor, xinv, fa, thr);
        gemm_stats<<<640, 256, 0, stream>>>(X, W, label, xinv, partial, cosl);
        finalize_rows<<<BB / 4, 256, 0, stream>>>(partial, cosl, fa, thr, rowres, NPART);
    }
    finalize_sum<<<1, BB, 0, stream>>>(rowres, out);
}

// Round 7
// 202.239 us; speedup vs baseline: 1.3928x; 1.3582x over previous
//
#include <hip/hip_runtime.h>
#include <hip/hip_bf16.h>
#include <math.h>

#define BB    1024
#define FIN   128
#define NOUT  10000
#define NBLK  79          // 128-col strips (fallback path)
#define NCB   158         // 64-col regions (Wbf layout)
#define NK    16
#define NPART (NCB * 2)   // per (cb, wn) partials = 316 (both paths)
#define LDX   136         // LDS stride (shorts) for the X tile

typedef __attribute__((ext_vector_type(8))) short short8;
typedef __attribute__((ext_vector_type(4))) float floatx4;

__device__ __forceinline__ unsigned packbf(float a, float b) {
    __hip_bfloat162 h = __float22bfloat162_rn(make_float2(a, b));
    union { __hip_bfloat162 h2; unsigned u; } v;
    v.h2 = h;
    return v.u;
}

// unpack bf16 pair, scale, repack
__device__ __forceinline__ unsigned scale2(unsigned p, float wi) {
    float lo = __uint_as_float(p << 16) * wi;
    float hi = __uint_as_float(p & 0xffff0000u) * wi;
    return packbf(lo, hi);
}

// async global->LDS, 16B per lane; LDS dest = wave-uniform base + lane*16.
__device__ __forceinline__ void async16(const void* g, void* l) {
    __builtin_amdgcn_global_load_lds(
        (const __attribute__((address_space(1))) unsigned int*)g,
        (__attribute__((address_space(3))) unsigned int*)l, 16, 0, 0);
}

// ---------------------------------------------------------------------------
// Kernel A (fallback path only)
__global__ void rowprep(const float* __restrict__ X, const float* __restrict__ factor,
                        float* __restrict__ xinv, float* __restrict__ fa_out,
                        float* __restrict__ thr_out) {
    int b = blockIdx.x;
    int lane = threadIdx.x;
    float v0 = X[b * FIN + lane];
    float v1 = X[b * FIN + 64 + lane];
    float s = v0 * v0 + v1 * v1;
    #pragma unroll
    for (int off = 32; off > 0; off >>= 1) s += __shfl_down(s, off);
    if (lane == 0) {
        xinv[b] = 1.0f / fmaxf(sqrtf(s), 1e-12f);
        float fa = powf(1.5f, factor[b] * (1.0f / 12.0f)) * 0.5f;
        fa_out[b] = fa;
        thr_out[b] = (float)M_PI - fa;
    }
}

// ---------------------------------------------------------------------------
// Kernel W v3 (proven): f-half staging (16 KB) + deferred winv scale at
// copy-out. LDS ~33.5 KB -> 4 blocks/CU. Wbf layout: per (k, cb64) 16 KB
// region [wn(2)][n2(2)][kk(4)][lane=q*16+l15][16B], holding bf16(W * winv),
// o = cb*64 + wn*32 + n2*16 + l15, f=(kk*4+q)*8..+7.
__global__ __launch_bounds__(256) void wconv(
    const float* __restrict__ W, unsigned char* __restrict__ Wbf,
    const float* __restrict__ X, const float* __restrict__ factor,
    float* __restrict__ xinv, float* __restrict__ fa_out, float* __restrict__ thr_out) {

    __shared__ float s[64 * 64];    // 16 KB: one f-half, [f][c] fp32
    __shared__ uint4 wout[1024];    // 16 KB packed (unscaled bf16)
    __shared__ float sq2[256];
    __shared__ float wis[64];

    const int tid = threadIdx.x;

    // rowprep tail blocks
    if (blockIdx.x >= NK * NCB) {
        int rb = blockIdx.x - NK * NCB;   // 0..15
        int w4 = tid >> 6, lane = tid & 63;
        for (int i = w4; i < 64; i += 4) {
            int row = rb * 64 + i;
            float v0 = X[row * FIN + lane];
            float v1 = X[row * FIN + 64 + lane];
            float ss = v0 * v0 + v1 * v1;
            #pragma unroll
            for (int off = 32; off > 0; off >>= 1) ss += __shfl_down(ss, off);
            if (lane == 0) {
                xinv[row] = 1.0f / fmaxf(sqrtf(ss), 1e-12f);
                float fa = powf(1.5f, factor[row] * (1.0f / 12.0f)) * 0.5f;
                fa_out[row] = fa;
                thr_out[row] = (float)M_PI - fa;
            }
        }
        return;
    }

    const int k  = blockIdx.x / NCB;
    const int cb = blockIdx.x - k * NCB;
    const int o0 = cb * 64;
    const int col = tid & 63, seg = tid >> 6;
    const int c   = tid >> 2, sub = tid & 3;
    const int wn_ = c >> 5, n2_ = (c >> 4) & 1, l15_ = c & 15;

    float sqacc = 0.0f;
    #pragma unroll
    for (int h = 0; h < 2; h++) {
        // stage f-half h: 64 rows x 64 cols fp32, coalesced
        #pragma unroll
        for (int it = 0; it < 4; it++) {
            int idx = it * 256 + tid;      // float4 idx 0..1023
            int f = idx >> 4, c4 = idx & 15;
            int o = o0 + c4 * 4;
            float4 v = make_float4(0.f, 0.f, 0.f, 0.f);
            if (o < NOUT)
                v = *(const float4*)(W + (size_t)(k * FIN + h * 64 + f) * NOUT + o);
            *(float4*)(s + f * 64 + c4 * 4) = v;
        }
        __syncthreads();
        // partial sumsq (16 f per thread)
        float ss = 0.0f;
        #pragma unroll
        for (int f2 = 0; f2 < 16; f2++) {
            float x = s[(seg * 16 + f2) * 64 + col];
            ss = fmaf(x, x, ss);
        }
        sqacc += ss;
        // pack this half UNSCALED
        #pragma unroll
        for (int i = 0; i < 2; i++) {
            int tcl = sub * 2 + i;          // 0..7
            int tcg = h * 8 + tcl;          // 0..15
            int kk = tcg >> 2, qq = tcg & 3;
            int fb = tcl * 8;               // LDS f-row base
            uint4 u;
            u.x = packbf(s[(fb + 0) * 64 + c], s[(fb + 1) * 64 + c]);
            u.y = packbf(s[(fb + 2) * 64 + c], s[(fb + 3) * 64 + c]);
            u.z = packbf(s[(fb + 4) * 64 + c], s[(fb + 5) * 64 + c]);
            u.w = packbf(s[(fb + 6) * 64 + c], s[(fb + 7) * 64 + c]);
            wout[wn_ * 512 + n2_ * 256 + kk * 64 + qq * 16 + l15_] = u;
        }
        __syncthreads();   // pack reads done before restage / before copy-out
    }
    sq2[tid] = sqacc;
    __syncthreads();
    if (tid < 64)
        wis[tid] = 1.0f / fmaxf(sqrtf(sq2[tid] + sq2[tid + 64] + sq2[tid + 128] + sq2[tid + 192]), 1e-12f);
    __syncthreads();

    // scaled coalesced copy-out
    unsigned char* dst = Wbf + ((size_t)k * NCB + cb) * 16384;
    #pragma unroll
    for (int i = 0; i < 4; i++) {
        int idx = i * 256 + tid;
        int ccol = ((idx >> 9) << 5) + (((idx >> 8) & 1) << 4) + (idx & 15);
        float wi = wis[ccol];
        uint4 u = wout[idx];
        uint4 r;
        r.x = scale2(u.x, wi);
        r.y = scale2(u.y, wi);
        r.z = scale2(u.z, wi);
        r.w = scale2(u.w, wi);
        *(uint4*)(dst + (size_t)idx * 16) = r;
    }
}

// ---------------------------------------------------------------------------
// Kernel B v7: r2-proven body (4m x 2n waves, 32x32 wave tiles, VGPR 48, no
// spill) with ONE structural change: pipeline stage = 2 k-tiles (32 KB), two
// buffers, 8 supersteps instead of 16. Rationale (r2 PMC): ratios fit an
// LDS-bound model (MfmaUtil 31 = 225/725cy, VALU 44 = 319/725) but absolute
// time is 3.3x the model -> ~65% of each k-step is all-pipes-idle sync
// overhead. Halve the sync points; LDS 64 KB -> 2 blocks/CU (up from ~1.45
// effective). Per superstep s: vmcnt(0) waits only loads(s) (issued a full
// superstep earlier, nothing newer outstanding -> no in-flight drain);
// s_barrier publishes; issue(s+1) into the other buffer (its readers
// finished before this barrier -> WAR-free); compute 2 k-tiles (32 MFMA).
__global__ __launch_bounds__(512, 2) void gemm_mx(
    const float* __restrict__ X, const unsigned char* __restrict__ Wbf,
    const int* __restrict__ label, const float* __restrict__ xinv,
    float2* __restrict__ partial, float* __restrict__ cosl) {

    __shared__ union {
        short xs[128 * LDX];   // 34816 B, X staging
        short bb[2][16384];    // 2 x 32 KB B buffers = 65536 B
    } u;

    const int tid  = threadIdx.x;
    const int lane = tid & 63;
    const int w    = tid >> 6;     // 0..7
    const int l15  = lane & 15;
    const int q    = lane >> 4;
    const int wm   = w & 3;        // 4 m-slots (32 rows each)
    const int wn   = w >> 2;       // 2 n-slots (32 cols each)

    // XCD-aware decode: ids {group*64 + y*8 + xcd} -> cb = group*8 + xcd
    const int id    = blockIdx.x;
    const int group = id >> 6;
    const int sub   = id & 63;
    const int cb    = group * 8 + (sub & 7);
    const int y     = sub >> 3;            // 0..7
    if (cb >= NCB) return;
    const int r0 = y * 128;
    const int o0 = cb * 64;

    // ---- stage X tile (128 rows) as bf16 with xinv folded ----
    #pragma unroll
    for (int it = 0; it < 8; it++) {
        int idx = it * 512 + tid;      // float4 index 0..4095
        int row = idx >> 5;
        int c4  = idx & 31;
        const float4 v = *(const float4*)(X + (size_t)(r0 + row) * FIN + c4 * 4);
        float xi = xinv[r0 + row];
        uint2 p;
        p.x = packbf(v.x * xi, v.y * xi);
        p.y = packbf(v.z * xi, v.w * xi);
        *(uint2*)(u.xs + row * LDX + c4 * 4) = p;
    }
    __syncthreads();

    short8 af[2][4];
    #pragma unroll
    for (int mt = 0; mt < 2; mt++)
        #pragma unroll
        for (int kk = 0; kk < 4; kk++)
            af[mt][kk] = *(const short8*)(u.xs + (wm * 32 + mt * 16 + l15) * LDX + kk * 32 + q * 8);
    __syncthreads();   // X area now reusable as B buffers

    // superstep staging: 32 KB (k-tiles 2s, 2s+1); wave w loads 4 KB
    auto issue2 = [&](int s, short* d) {
        const unsigned char* g = Wbf + ((size_t)(2 * s) * NCB + cb) * 16384
                                 + (size_t)w * 2048 + (size_t)lane * 16;
        short* dw = d + w * 1024;
        async16(g, dw);
        async16(g + 1024, dw + 512);
        const unsigned char* g2 = g + (size_t)NCB * 16384;   // k-tile 2s+1
        short* dw2 = d + 8192 + w * 1024;
        async16(g2, dw2);
        async16(g2 + 1024, dw2 + 512);
    };

    short* cur = u.bb[0];
    short* nxt = u.bb[1];

    issue2(0, cur);

    floatx4 maxv[2][2];
    #pragma unroll
    for (int mt = 0; mt < 2; mt++)
        #pragma unroll
        for (int n2 = 0; n2 < 2; n2++)
            #pragma unroll
            for (int r = 0; r < 4; r++)
                maxv[mt][n2][r] = -INFINITY;

    for (int s = 0; s < NK / 2; s++) {
        // loads(s) are the only outstanding VMEM ops; issued a full superstep
        // ago (or at prologue for s=0) -> wait is cheap
        asm volatile("s_waitcnt vmcnt(0)" ::: "memory");
        __builtin_amdgcn_s_barrier();
        if (s < NK / 2 - 1) issue2(s + 1, nxt);

        #pragma unroll
        for (int half = 0; half < 2; half++) {
            const short* wt = cur + half * 8192;

            floatx4 acc[2][2];
            #pragma unroll
            for (int mt = 0; mt < 2; mt++)
                #pragma unroll
                for (int n2 = 0; n2 < 2; n2++)
                    acc[mt][n2] = (floatx4){0.f, 0.f, 0.f, 0.f};
            #pragma unroll
            for (int kk = 0; kk < 4; kk++) {
                short8 bf[2];
                #pragma unroll
                for (int n2 = 0; n2 < 2; n2++)
                    bf[n2] = *(const short8*)(wt + wn * 4096 + n2 * 2048 + kk * 512 + lane * 8);
                #pragma unroll
                for (int mt = 0; mt < 2; mt++)
                    #pragma unroll
                    for (int n2 = 0; n2 < 2; n2++)
                        acc[mt][n2] = __builtin_amdgcn_mfma_f32_16x16x32_bf16(
                            af[mt][kk], bf[n2], acc[mt][n2], 0, 0, 0);
            }
            #pragma unroll
            for (int mt = 0; mt < 2; mt++)
                #pragma unroll
                for (int n2 = 0; n2 < 2; n2++)
                    #pragma unroll
                    for (int r = 0; r < 4; r++)
                        maxv[mt][n2][r] = fmaxf(maxv[mt][n2][r], acc[mt][n2][r]);
        }

        // swap buffers
        short* t = cur; cur = nxt; nxt = t;
    }

    // ---- epilogue: fixed-reference partial softmax (label col excluded) ----
    #pragma unroll
    for (int mt = 0; mt < 2; mt++) {
        #pragma unroll
        for (int rr = 0; rr < 4; rr++) {
            int row = r0 + wm * 32 + mt * 16 + q * 4 + rr;
            int lb = label[row];
            float m = -1e30f, sum = 0.f;
            #pragma unroll
            for (int n2 = 0; n2 < 2; n2++) {
                int o = o0 + wn * 32 + n2 * 16 + l15;
                if (o < NOUT) {
                    float cc = maxv[mt][n2][rr];
                    if (o == lb) {
                        cosl[row] = cc;   // unique writer grid-wide
                    } else {
                        float l = 64.0f * fminf(fmaxf(cc, -1.0f + 1e-6f), 1.0f - 1e-6f);
                        sum += __expf(l - 64.0f);
                        m = fmaxf(m, l);
                    }
                }
            }
            #pragma unroll
            for (int off = 1; off <= 8; off <<= 1) {
                sum += __shfl_xor(sum, off);
                m = fmaxf(m, __shfl_xor(m, off));
            }
            if (l15 == 0)
                partial[(size_t)row * NPART + cb * 2 + wn] = make_float2(m, sum);
        }
    }
}

// ---------------------------------------------------------------------------
// Fallback GEMM (used when ws_size can't hold Wbf). Stride NPART partials.
__global__ __launch_bounds__(256, 2) void gemm_stats(
    const float* __restrict__ X, const float* __restrict__ W,
    const int* __restrict__ label, const float* __restrict__ xinv,
    float2* __restrict__ partial, float* __restrict__ cosl) {

    __shared__ short xs[128 * LDX];
    __shared__ short wt[128 * LDX];
    __shared__ float sqs[128][2];

    const int tid  = threadIdx.x;
    const int lane = tid & 63;
    const int w    = tid >> 6;
    const int l15  = lane & 15;
    const int q    = lane >> 4;
    const int wm   = w & 1;
    const int wn   = w >> 1;

    const int id    = blockIdx.x;
    const int group = id >> 6;
    const int sub   = id & 63;
    const int jb    = group * 8 + (sub & 7);
    const int y     = sub >> 3;
    if (jb >= NBLK) return;
    const int r0 = y * 128;
    const int o0 = jb * 128;

    #pragma unroll
    for (int it = 0; it < 16; it++) {
        int idx = it * 256 + tid;
        int row = idx >> 5;
        int c4  = idx & 31;
        const float4 v = *(const float4*)(X + (size_t)(r0 + row) * FIN + c4 * 4);
        uint2 p;
        p.x = packbf(v.x, v.y);
        p.y = packbf(v.z, v.w);
        *(uint2*)(xs + row * LDX + c4 * 4) = p;
    }

    const int st_o = (w & 1) * 64 + lane;
    const int st_f = (w >> 1) * 64;
    const int st_h = w >> 1;
    const int go   = o0 + st_o;
    const bool ov  = go < NOUT;

    float rw[64];
    {
        const float* Wp = W + (size_t)st_f * NOUT + go;
        #pragma unroll
        for (int g = 0; g < 16; g++)
            #pragma unroll
            for (int cc = 0; cc < 4; cc++)
                rw[g * 4 + cc] = ov ? Wp[(size_t)(g * 4 + cc) * NOUT] : 0.0f;
    }
    __syncthreads();

    short8 af[4][4];
    #pragma unroll
    for (int mt = 0; mt < 4; mt++)
        #pragma unroll
        for (int kk = 0; kk < 4; kk++)
            af[mt][kk] = *(const short8*)(xs + (wm * 64 + mt * 16 + l15) * LDX + kk * 32 + q * 8);

    floatx4 maxv[4][4];
    #pragma unroll
    for (int mt = 0; mt < 4; mt++)
        #pragma unroll
        for (int nt = 0; nt < 4; nt++)
            #pragma unroll
            for (int r = 0; r < 4; r++)
                maxv[mt][nt][r] = -INFINITY;

    for (int k = 0; k < NK; k++) {
        float sq = 0.0f;
        uint2 pk[16];
        #pragma unroll
        for (int g = 0; g < 16; g++) {
            float a0 = rw[g * 4 + 0], a1 = rw[g * 4 + 1];
            float a2 = rw[g * 4 + 2], a3 = rw[g * 4 + 3];
            sq = fmaf(a0, a0, sq); sq = fmaf(a1, a1, sq);
            sq = fmaf(a2, a2, sq); sq = fmaf(a3, a3, sq);
            pk[g].x = packbf(a0, a1);
            pk[g].y = packbf(a2, a3);
        }
        __syncthreads();
        #pragma unroll
        for (int g = 0; g < 16; g++)
            *(uint2*)(wt + st_o * LDX + st_f + g * 4) = pk[g];
        sqs[st_o][st_h] = sq;
        __syncthreads();

        if (k < NK - 1) {
            const float* Wn = W + ((size_t)(k + 1) * FIN + st_f) * NOUT + go;
            #pragma unroll
            for (int g = 0; g < 16; g++)
                #pragma unroll
                for (int cc = 0; cc < 4; cc++)
                    rw[g * 4 + cc] = ov ? Wn[(size_t)(g * 4 + cc) * NOUT] : 0.0f;
        }

        float wv[4];
        #pragma unroll
        for (int nt = 0; nt < 4; nt++) {
            int colx = wn * 64 + nt * 16 + l15;
            wv[nt] = 1.0f / fmaxf(sqrtf(sqs[colx][0] + sqs[colx][1]), 1e-12f);
        }

        #pragma unroll
        for (int h = 0; h < 2; h++) {
            floatx4 acc[4][2];
            #pragma unroll
            for (int mt = 0; mt < 4; mt++) {
                acc[mt][0] = (floatx4){0.f, 0.f, 0.f, 0.f};
                acc[mt][1] = (floatx4){0.f, 0.f, 0.f, 0.f};
            }
            #pragma unroll
            for (int kk = 0; kk < 4; kk++) {
                short8 bf0 = *(const short8*)(wt + (wn * 64 + (h * 2 + 0) * 16 + l15) * LDX + kk * 32 + q * 8);
                short8 bf1 = *(const short8*)(wt + (wn * 64 + (h * 2 + 1) * 16 + l15) * LDX + kk * 32 + q * 8);
                #pragma unroll
                for (int mt = 0; mt < 4; mt++) {
                    acc[mt][0] = __builtin_amdgcn_mfma_f32_16x16x32_bf16(af[mt][kk], bf0, acc[mt][0], 0, 0, 0);
                    acc[mt][1] = __builtin_amdgcn_mfma_f32_16x16x32_bf16(af[mt][kk], bf1, acc[mt][1], 0, 0, 0);
                }
            }
            #pragma unroll
            for (int mt = 0; mt < 4; mt++)
                #pragma unroll
                for (int n2 = 0; n2 < 2; n2++)
                    #pragma unroll
                    for (int r = 0; r < 4; r++)
                        maxv[mt][h * 2 + n2][r] =
                            fmaxf(maxv[mt][h * 2 + n2][r], acc[mt][n2][r] * wv[h * 2 + n2]);
        }
    }

    #pragma unroll
    for (int mt = 0; mt < 4; mt++) {
        #pragma unroll
        for (int rr = 0; rr < 4; rr++) {
            int row = r0 + wm * 64 + mt * 16 + q * 4 + rr;
            float xi = xinv[row];
            int lb = label[row];
            float m = -1e30f, sum = 0.f;
            #pragma unroll
            for (int nt = 0; nt < 4; nt++) {
                int o = o0 + wn * 64 + nt * 16 + l15;
                if (o < NOUT) {
                    float cc = maxv[mt][nt][rr] * xi;
                    if (o == lb) {
                        cosl[row] = cc;
                    } else {
                        float l = 64.0f * fminf(fmaxf(cc, -1.0f + 1e-6f), 1.0f - 1e-6f);
                        sum += __expf(l - 64.0f);
                        m = fmaxf(m, l);
                    }
                }
            }
            #pragma unroll
            for (int off = 1; off <= 8; off <<= 1) {
                sum += __shfl_xor(sum, off);
                m = fmaxf(m, __shfl_xor(m, off));
            }
            if (l15 == 0) {
                partial[(size_t)row * NPART + jb * 4 + wn * 2 + 0] = make_float2(m, sum);
                partial[(size_t)row * NPART + jb * 4 + wn * 2 + 1] = make_float2(-1e30f, 0.f);
            }
        }
    }
}

// ---------------------------------------------------------------------------
// Kernel C1: per-row combine (fixed-ref: plain sum+max) + margin. np = stride.
__global__ void finalize_rows(const float2* __restrict__ partial, const float* __restrict__ cosl,
                              const float* __restrict__ fa, const float* __restrict__ thr,
                              float2* __restrict__ rowres, int np) {
    int w = threadIdx.x >> 6;
    int lane = threadIdx.x & 63;
    int b = blockIdx.x * 4 + w;
    float m = -1e30f, s = 0.0f;
    for (int j = lane; j < np; j += 64) {
        float2 p = partial[(size_t)b * np + j];
        s += p.y;
        m = fmaxf(m, p.x);
    }
    #pragma unroll
    for (int off = 1; off < 64; off <<= 1) {
        s += __shfl_xor(s, off);
        m = fmaxf(m, __shfl_xor(m, off));
    }
    if (lane == 0) {
        float c = fminf(fmaxf(cosl[b], -1.0f + 1e-6f), 1.0f - 1e-6f);
        float theta = acosf(c);
        float ll = (theta > thr[b]) ? 64.0f * c : 64.0f * cosf(theta + fa[b]);
        float S = s + __expf(ll - 64.0f);
        float loss = 64.0f + logf(S) - ll;
        rowres[b] = make_float2(loss, (ll > m) ? 100.0f : 0.0f);
    }
}

// Kernel C2: deterministic tree reduce of 1024 rows -> 2 scalars.
__global__ void finalize_sum(const float2* __restrict__ rowres, float* __restrict__ out) {
    __shared__ float sl[1024];
    __shared__ float sc[1024];
    int b = threadIdx.x;
    float2 v = rowres[b];
    sl[b] = v.x;
    sc[b] = v.y;
    __syncthreads();
    for (int st = 512; st > 0; st >>= 1) {
        if (b < st) { sl[b] += sl[b + st]; sc[b] += sc[b + st]; }
        __syncthreads();
    }
    if (b == 0) {
        out[0] = sl[0] * (1.0f / 1024.0f);
        out[1] = sc[0] * (1.0f / 1024.0f);
    }
}

// ---------------------------------------------------------------------------
extern "C" void kernel_launch(void* const* d_in, const int* in_sizes, int n_in,
                              void* d_out, int out_size, void* d_ws, size_t ws_size,
                              hipStream_t stream) {
    const float* X      = (const float*)d_in[0];
    const float* factor = (const float*)d_in[1];
    const int*   label  = (const int*)d_in[2];
    const float* W      = (const float*)d_in[3];
    float* out = (float*)d_out;
    float* ws  = (float*)d_ws;

    float*  xinv = ws;                        // 1024
    float*  fa   = ws + 1024;                 // 1024
    float*  thr  = ws + 2048;                 // 1024
    float*  cosl = ws + 3072;                 // 1024
    float2* rowres = (float2*)(ws + 4096);    // 1024 float2
    float2* partial = (float2*)(ws + 6144);   // 1024 x 316 float2 (~2.6 MB)
    unsigned char* Wbf = (unsigned char*)d_ws + 4 * 1024 * 1024;  // 41.4 MB

    const size_t wbf_bytes = (size_t)NK * NCB * 16384;
    const size_t need = 4ull * 1024 * 1024 + wbf_bytes;

    if (ws_size >= need) {
        wconv<<<NK * NCB + 16, 256, 0, stream>>>(W, Wbf, X, factor, xinv, fa, thr);
        gemm_mx<<<1280, 512, 0, stream>>>(X, Wbf, label, xinv, partial, cosl);
    } else {
        rowprep<<<BB, 64, 0, stream>>>(X, factor, xinv, fa, thr);
        gemm_stats<<<640, 256, 0, stream>>>(X, W, label, xinv, partial, cosl);
    }
    finalize_rows<<<BB / 4, 256, 0, stream>>>(partial, cosl, fa, thr, rowres, NPART);
    finalize_sum<<<1, BB, 0, stream>>>(rowres, out);
}